// Round 7
// baseline (355.248 us; speedup 1.0000x reference)
//
#include <hip/hip_runtime.h>
#include <hip/hip_bf16.h>
#include <stdint.h>

#define HD 128
#define GD 64
#define OUTD 16
#define PCH 32  // pool chunks per graph

typedef unsigned short u16;
typedef unsigned int u32;
typedef __attribute__((ext_vector_type(8))) short short8;
typedef __attribute__((ext_vector_type(4))) float f32x4;
typedef __attribute__((ext_vector_type(4))) unsigned short u16x4;

__device__ __forceinline__ float bf2f(u16 u) {
  union { uint32_t i; float f; } v; v.i = ((uint32_t)u) << 16; return v.f;
}
__device__ __forceinline__ u16 f2bf(float f) {
  union { __hip_bfloat16 h; u16 u; } v; v.h = __float2bfloat16(f); return v.u;
}

// exclusive scan of 256 per-thread values via LDS (Hillis-Steele).
__device__ __forceinline__ u32 excl_scan256(u32 v, u32* s, int t, u32* total) {
  s[t] = v;
  __syncthreads();
#pragma unroll
  for (int off = 1; off < 256; off <<= 1) {
    u32 x = (t >= off) ? s[t - off] : 0u;
    __syncthreads();
    s[t] += x;
    __syncthreads();
  }
  u32 incl = s[t];
  u32 tot = s[255];
  __syncthreads();
  *total = tot;
  return incl - v;
}

__device__ __forceinline__ int detect_is64(const int* ei) {
  int all0 = 1;
  for (int k = 1; k < 128; k += 2) all0 &= (ei[k] == 0);
  return all0;
}

// K1: per-block LDS histogram over col-buckets (col>>8); no global atomics.
__global__ __launch_bounds__(256)
void hist_k(const int* __restrict__ ei, const int* __restrict__ bt,
            int* __restrict__ b32, int* __restrict__ Hist, int E, int N) {
  __shared__ int h[256];
  __shared__ int s_is64;
  h[threadIdx.x] = 0;
  if (threadIdx.x == 0) s_is64 = detect_is64(ei);
  __syncthreads();
  int is64 = s_is64;
  int i = blockIdx.x * 256 + threadIdx.x;
  if (i < E) {
    int c = is64 ? ei[2 * (E + i)] : ei[E + i];
    c = (c < 0) ? 0 : (c >= N ? N - 1 : c);
    atomicAdd(&h[c >> 8], 1);              // LDS atomic
  }
  if (i < N) {
    int v = is64 ? bt[2 * i] : bt[i];
    b32[i] = (v < 0) ? 0 : (v >= GD ? GD - 1 : v);
  }
  __syncthreads();
  Hist[(size_t)blockIdx.x * 256 + threadIdx.x] = h[threadIdx.x];
}

// K2: for bucket b = blockIdx, exclusive-scan Hist[*][b] across blocks.
__global__ __launch_bounds__(256)
void scan_k(const int* __restrict__ Hist, int* __restrict__ Off,
            int* __restrict__ totals, int nblk) {
  __shared__ u32 s[256];
  int b = blockIdx.x, t = threadIdx.x;
  int chunk = (nblk + 255) >> 8;
  int i0 = t * chunk;
  int i1 = i0 + chunk; if (i1 > nblk) i1 = nblk;
  u32 part = 0;
  for (int i = i0; i < i1; ++i) part += (u32)Hist[(size_t)i * 256 + b];
  u32 tot;
  u32 run = excl_scan256(part, s, t, &tot);
  for (int i = i0; i < i1; ++i) {
    u32 h = (u32)Hist[(size_t)i * 256 + b];
    Off[(size_t)i * 256 + b] = (int)run;
    run += h;
  }
  if (t == 0) totals[b] = (int)tot;
}

// K2b: bucketBase = exclusive scan of totals; offs[N] = E.
__global__ __launch_bounds__(256)
void base_k(const int* __restrict__ totals, int* __restrict__ bucketBase,
            int* __restrict__ offs, int nbuk, int N, int E) {
  __shared__ u32 s[256];
  int t = threadIdx.x;
  u32 v = (t < nbuk) ? (u32)totals[t] : 0u;
  u32 tot;
  u32 excl = excl_scan256(v, s, t, &tot);
  bucketBase[t] = (int)excl;
  if (t == 0) offs[N] = E;
}

// K3: scatter edges into bucket-partitioned tmp; LDS cursors only.
__global__ __launch_bounds__(256)
void scat_k(const int* __restrict__ ei, const float* __restrict__ ea,
            const int* __restrict__ bucketBase, const int* __restrict__ Off,
            int2* __restrict__ tmp, int E, int N, int nbuk) {
  __shared__ u32 cur[256];
  __shared__ int s_is64;
  int t = threadIdx.x;
  if (t == 0) s_is64 = detect_is64(ei);
  cur[t] = (t < nbuk)
         ? (u32)(bucketBase[t] + Off[(size_t)blockIdx.x * 256 + t]) : 0u;
  __syncthreads();
  int is64 = s_is64;
  int i = blockIdx.x * 256 + t;
  if (i >= E) return;
  int r = is64 ? ei[2 * i] : ei[i];
  int c = is64 ? ei[2 * (E + i)] : ei[E + i];
  r = (r < 0) ? 0 : (r >= N ? N - 1 : r);
  c = (c < 0) ? 0 : (c >= N ? N - 1 : c);
  float a = ea[i];
  float w = isnan(a) ? 0.f : fabsf(a);
  u32 pos = atomicAdd(&cur[c >> 8], 1u);  // LDS atomic
  tmp[pos] = make_int2((int)(((u32)(c & 255) << 16) | (u32)r), __float_as_int(w));
}

// K4: per-bucket column sort into final csc + offs.
__global__ __launch_bounds__(256)
void sort_k(const int2* __restrict__ tmp, const int* __restrict__ bucketBase,
            int2* __restrict__ csc, int* __restrict__ offs, int N) {
  __shared__ u32 cnt[256];
  __shared__ u32 s[256];
  __shared__ u32 cur[256];
  int b = blockIdx.x, t = threadIdx.x;
  int s0 = bucketBase[b], s1 = bucketBase[b + 1];
  cnt[t] = 0;
  __syncthreads();
  for (int p = s0 + t; p < s1; p += 256) {
    u32 rc = (u32)tmp[p].x;
    atomicAdd(&cnt[rc >> 16], 1u);
  }
  __syncthreads();
  u32 tot;
  u32 excl = excl_scan256(cnt[t], s, t, &tot);
  u32 st = (u32)s0 + excl;
  int col = (b << 8) + t;
  if (col < N) offs[col] = (int)st;
  cur[t] = st;
  __syncthreads();
  for (int p = s0 + t; p < s1; p += 256) {
    int2 r = tmp[p];
    u32 rc = (u32)r.x;
    u32 pos = atomicAdd(&cur[rc >> 16], 1u);
    csc[pos] = make_int2((int)(rc & 0xFFFFu), r.y);
  }
}

// merged: dinv + weight transpose/convert
__global__ void deg_convw_k(const int* __restrict__ offs, const int2* __restrict__ csc,
                            float* __restrict__ dinv,
                            const float* __restrict__ W0, const float* __restrict__ W1,
                            const float* __restrict__ W2, u16* __restrict__ Wt, int N) {
  int i = blockIdx.x * 256 + threadIdx.x;
  if (i < 3 * HD * HD) {
    int l = i / (HD * HD);
    int r = i - l * (HD * HD);
    int n = r >> 7, k = r & 127;
    const float* W = (l == 0) ? W0 : (l == 1) ? W1 : W2;
    Wt[i] = f2bf(W[k * HD + n]);
  }
  if (i < N) {
    int p = offs[i], pe = offs[i + 1];
    float s = 0.f;
    for (; p < pe; ++p) s += __int_as_float(csc[p].y);
    dinv[i] = rsqrtf(s + 1.0f);
  }
}

// ---- shared MFMA core (operands swapped: mfma(W_frag, A_frag)).
__device__ __forceinline__ void gemm_core(const u16* sw, const short8* afr,
                                          int m, int qd, int arow,
                                          const float* __restrict__ dinv,
                                          u16* __restrict__ B, int N) {
  const bool ok = (arow < N);
  const float dr = ok ? dinv[arow] : 0.f;
#pragma unroll
  for (int c = 0; c < 8; ++c) {
    f32x4 acc = {0.f, 0.f, 0.f, 0.f};
    const int n = c * 16 + m;
#pragma unroll
    for (int s = 0; s < 4; ++s) {
      short8 bfr = *(const short8*)(sw + n * 136 + 32 * s + 8 * qd);
      acc = __builtin_amdgcn_mfma_f32_16x16x32_bf16(bfr, afr[s], acc, 0, 0, 0);
    }
    if (ok) {
      u16x4 o;
#pragma unroll
      for (int r = 0; r < 4; ++r) o[r] = f2bf(dr * acc[r]);
      *(u16x4*)(B + (size_t)arow * HD + c * 16 + qd * 4) = o;
    }
  }
}

__device__ __forceinline__ void stage_w(const u16* __restrict__ Wt, u16* sw, int t) {
  const uint32_t* src = (const uint32_t*)Wt;
  uint32_t* dst = (uint32_t*)sw;
#pragma unroll
  for (int k = 0; k < 32; ++k) {
    int q = t + k * 256;
    int r = q >> 6;
    int u = q & 63;
    dst[r * 68 + u] = src[r * 64 + u];
  }
}

// layer-0 GEMM with fused h0 construction: reads x[N,64] fp32 directly.
__global__ __launch_bounds__(256)
void gemm0_k(const float* __restrict__ x, const u16* __restrict__ Wt,
             const float* __restrict__ dinv, u16* __restrict__ B, int N) {
  __shared__ u16 sw[128 * 136];
  const int t = threadIdx.x;
  stage_w(Wt, sw, t);
  __syncthreads();
  const int w = t >> 6;
  const int lane = t & 63;
  const int m = lane & 15;
  const int qd = lane >> 4;
  const int arow = blockIdx.x * 64 + w * 16 + m;
  short8 afr[4];
  if (arow < N) {
    const float* xp = x + (size_t)arow * 64;
    float v0[8], v1[8];
    *(float4*)&v0[0] = *(const float4*)(xp + 8 * qd);
    *(float4*)&v0[4] = *(const float4*)(xp + 8 * qd + 4);
    *(float4*)&v1[0] = *(const float4*)(xp + 32 + 8 * qd);
    *(float4*)&v1[4] = *(const float4*)(xp + 32 + 8 * qd + 4);
#pragma unroll
    for (int j = 0; j < 8; ++j) {
      bool n0 = isnan(v0[j]), n1 = isnan(v1[j]);
      afr[0][j] = (short)f2bf(n0 ? 0.f : v0[j]);
      afr[1][j] = (short)f2bf(n1 ? 0.f : v1[j]);
      afr[2][j] = (short)(n0 ? 0x3F80 : 0);
      afr[3][j] = (short)(n1 ? 0x3F80 : 0);
    }
  } else {
    short8 z = {0, 0, 0, 0, 0, 0, 0, 0};
#pragma unroll
    for (int s = 0; s < 4; ++s) afr[s] = z;
  }
  gemm_core(sw, afr, m, qd, arow, dinv, B, N);
}

// generic GEMM: B = dinv-scaled rows of (A @ W), A bf16
__global__ __launch_bounds__(256)
void gemm_k(const u16* __restrict__ A, const u16* __restrict__ Wt,
            const float* __restrict__ dinv, u16* __restrict__ B, int N) {
  __shared__ u16 sw[128 * 136];
  const int t = threadIdx.x;
  stage_w(Wt, sw, t);
  __syncthreads();
  const int w = t >> 6;
  const int lane = t & 63;
  const int m = lane & 15;
  const int qd = lane >> 4;
  const int arow = blockIdx.x * 64 + w * 16 + m;
  short8 afr[4];
  if (arow < N) {
    const short8* ap = (const short8*)(A + (size_t)arow * HD);
#pragma unroll
    for (int s = 0; s < 4; ++s) afr[s] = ap[4 * s + qd];
  } else {
    short8 z = {0, 0, 0, 0, 0, 0, 0, 0};
#pragma unroll
    for (int s = 0; s < 4; ++s) afr[s] = z;
  }
  gemm_core(sw, afr, m, qd, arow, dinv, B, N);
}

// Fused: A[n] = BN?ReLU( dinv[n]*(C[n] + sum_in w*C[row]) + bias )
// Feature-QUARTER split with XCD-pair affinity: quarter q (32 feats) runs
// only on XCD slots {2q,2q+1} (blockIdx&7 round-robin heuristic).  Per-quarter
// gather working set = N*64B = 3.2MB < 4MB per-XCD L2 -> B-quarter L2-resident.
// 4 lanes/node, 16B gathers.  (Re-test of round-4 agg on atomic-free base.)
__global__ __launch_bounds__(256)
void aggregate_k(const int* __restrict__ offs, const int2* __restrict__ csc,
                 const u16* __restrict__ B, const float* __restrict__ dinv,
                 const float* __restrict__ bias, const float* __restrict__ gamma,
                 const float* __restrict__ beta, const float* __restrict__ mean,
                 const float* __restrict__ var, int do_bn,
                 u16* __restrict__ A, int N, int nbq) {
  int b = blockIdx.x;
  int slot = b & 7;
  int qtr = slot >> 1;                    // feature quarter 0..3
  int j = ((b >> 3) << 1) + (slot & 1);   // node-block index within quarter
  if (j >= nbq) return;
  int n = j * 64 + (threadIdx.x >> 2);
  if (n >= N) return;
  int f8 = ((threadIdx.x & 3) << 3) + (qtr << 5);
  float acc[8];
  short8 bu = *(const short8*)(B + (size_t)n * HD + f8);
#pragma unroll
  for (int u = 0; u < 8; ++u) acc[u] = bf2f((u16)bu[u]);   // self term C[n]

  int p = offs[n], pe = offs[n + 1];
  for (; p + 7 < pe; p += 8) {
    int2 e[8];
    short8 h[8];
#pragma unroll
    for (int u = 0; u < 8; ++u) e[u] = csc[p + u];
#pragma unroll
    for (int u = 0; u < 8; ++u) h[u] = *(const short8*)(B + (size_t)e[u].x * HD + f8);
#pragma unroll
    for (int u = 0; u < 8; ++u) {
      float w = __int_as_float(e[u].y);
#pragma unroll
      for (int q = 0; q < 8; ++q) acc[q] += w * bf2f((u16)h[u][q]);
    }
  }
  for (; p + 1 < pe; p += 2) {
    int2 e0 = csc[p], e1 = csc[p + 1];
    short8 h0 = *(const short8*)(B + (size_t)e0.x * HD + f8);
    short8 h1 = *(const short8*)(B + (size_t)e1.x * HD + f8);
    float w0 = __int_as_float(e0.y), w1 = __int_as_float(e1.y);
#pragma unroll
    for (int q = 0; q < 8; ++q)
      acc[q] += w0 * bf2f((u16)h0[q]) + w1 * bf2f((u16)h1[q]);
  }
  if (p < pe) {
    int2 e0 = csc[p];
    float w0 = __int_as_float(e0.y);
    short8 h0 = *(const short8*)(B + (size_t)e0.x * HD + f8);
#pragma unroll
    for (int q = 0; q < 8; ++q) acc[q] += w0 * bf2f((u16)h0[q]);
  }
  float dn = dinv[n];
#pragma unroll
  for (int q = 0; q < 8; ++q) acc[q] = dn * acc[q] + bias[f8 + q];
  if (do_bn) {
#pragma unroll
    for (int q = 0; q < 8; ++q) {
      float s = gamma[f8 + q] * rsqrtf(var[f8 + q] + 1e-5f);
      float v = (acc[q] - mean[f8 + q]) * s + beta[f8 + q];
      acc[q] = v > 0.f ? v : 0.f;
    }
  }
  short8 o;
#pragma unroll
  for (int q = 0; q < 8; ++q) o[q] = (short)f2bf(acc[q]);
  *(short8*)(A + (size_t)n * HD + f8) = o;
}

__device__ __forceinline__ int seg_lower_bound(const int* b32, int N, int b) {
  int lo = 0, hi = N;
  while (lo < hi) {
    int mid = (lo + hi) >> 1;
    if (b32[mid] < b) lo = mid + 1; else hi = mid;
  }
  return lo;
}

// two-stage mean pool, stage 1 (bf16 input); atomic-free partials.
__global__ __launch_bounds__(128)
void pool1_k(const u16* __restrict__ A, const int* __restrict__ b32,
             float* __restrict__ part, int N) {
  __shared__ int sb[2];
  int b = blockIdx.y;
  if (threadIdx.x < 2) sb[threadIdx.x] = seg_lower_bound(b32, N, b + threadIdx.x);
  __syncthreads();
  int s = sb[0], e = sb[1];
  int j = threadIdx.x;
  float a0 = 0.f, a1 = 0.f, a2 = 0.f, a3 = 0.f;
  int len = e - s;
  if (len > 0) {
    int nch = gridDim.x;
    int ch = (len + nch - 1) / nch;
    int lo = s + blockIdx.x * ch;
    int hi = lo + ch; if (hi > e) hi = e;
    int n = lo;
    for (; n + 3 < hi; n += 4) {
      a0 += bf2f(A[(size_t)(n + 0) * HD + j]);
      a1 += bf2f(A[(size_t)(n + 1) * HD + j]);
      a2 += bf2f(A[(size_t)(n + 2) * HD + j]);
      a3 += bf2f(A[(size_t)(n + 3) * HD + j]);
    }
    for (; n < hi; ++n) a0 += bf2f(A[(size_t)n * HD + j]);
  }
  part[((size_t)b * PCH + blockIdx.x) * HD + j] = (a0 + a1) + (a2 + a3);
}

// out = gelu((mean)@mW1+mb1) @ mW2 + mb2 ; mean from PCH partials
__global__ __launch_bounds__(128)
void mlp_k(const float* __restrict__ part, const int* __restrict__ b32,
           const float* __restrict__ mW1, const float* __restrict__ mb1,
           const float* __restrict__ mW2, const float* __restrict__ mb2,
           float* __restrict__ out, int N) {
  __shared__ float sg[128];
  __shared__ float st[128];
  __shared__ int sb[2];
  int b = blockIdx.x, j = threadIdx.x;
  if (j < 2) sb[j] = seg_lower_bound(b32, N, b + j);
  __syncthreads();
  int cnt = sb[1] - sb[0];
  float inv = 1.0f / (float)(cnt > 0 ? cnt : 1);
  float s0 = 0.f;
#pragma unroll
  for (int c = 0; c < PCH; ++c) s0 += part[((size_t)b * PCH + c) * HD + j];
  sg[j] = s0 * inv;
  __syncthreads();
  float s = mb1[j];
#pragma unroll 4
  for (int i = 0; i < 128; ++i) s += sg[i] * mW1[i * 128 + j];
  float ge = 0.5f * s * (1.0f + erff(s * 0.70710678118654752f));
  st[j] = ge;
  __syncthreads();
  if (j < OUTD) {
    float o = mb2[j];
#pragma unroll 4
    for (int k = 0; k < 128; ++k) o += st[k] * mW2[k * OUTD + j];
    out[b * OUTD + j] = o;
  }
}

// ---------------------------------------------------------------- launch
extern "C" void kernel_launch(void* const* d_in, const int* in_sizes, int n_in,
                              void* d_out, int out_size, void* d_ws, size_t ws_size,
                              hipStream_t stream) {
  const float* x   = (const float*)d_in[0];
  const int* ei    = (const int*)d_in[1];
  const float* ea  = (const float*)d_in[2];
  const int* bt    = (const int*)d_in[3];
  const float* W0  = (const float*)d_in[4];
  const float* b0  = (const float*)d_in[5];
  const float* W1  = (const float*)d_in[6];
  const float* b1  = (const float*)d_in[7];
  const float* W2  = (const float*)d_in[8];
  const float* b2  = (const float*)d_in[9];
  const float* bng = (const float*)d_in[10];
  const float* bnb = (const float*)d_in[11];
  const float* bnm = (const float*)d_in[12];
  const float* bnv = (const float*)d_in[13];
  const float* mW1 = (const float*)d_in[14];
  const float* mb1 = (const float*)d_in[15];
  const float* mW2 = (const float*)d_in[16];
  const float* mb2 = (const float*)d_in[17];
  float* out = (float*)d_out;

  const int N = in_sizes[0] / 64;      // 50000  (rows fit in 16 bits)
  const int E = in_sizes[2];           // 800000

  char* ws = (char*)d_ws;
  size_t NB2 = (size_t)N * HD * 2;     // bf16 feature buffer
  u16* A       = (u16*)(ws);
  u16* B       = (u16*)(ws + NB2);
  char* q      = ws + 2 * NB2;
  float* part  = (float*)q;            q += (size_t)GD * PCH * HD * 4;
  u16* Wt      = (u16*)q;              q += (size_t)3 * HD * HD * 2;
  int2* csc    = (int2*)q;             q += (size_t)E * 8;
  int2* tmp    = (int2*)q;             q += (size_t)E * 8;
  int gE  = (E + 255) / 256;
  int*   Hist  = (int*)q;              q += (size_t)gE * 256 * 4;
  int*   Off   = (int*)q;              q += (size_t)gE * 256 * 4;
  int*   totals= (int*)q;              q += 256 * 4;
  int*   bBase = (int*)q;              q += 260 * 4;
  float* dinv  = (float*)q;            q += (size_t)N * 4;
  int*   offs  = (int*)q;              q += (size_t)(N + 2) * 4;
  int*   b32   = (int*)q;              q += (size_t)N * 4;

  dim3 blk(256);
  int gN   = (N + 255) / 256;
  int nbuk = gN;                       // col buckets (col>>8)

  hist_k<<<gE, blk, 0, stream>>>(ei, bt, b32, Hist, E, N);
  scan_k<<<nbuk, blk, 0, stream>>>(Hist, Off, totals, gE);
  base_k<<<1, blk, 0, stream>>>(totals, bBase, offs, nbuk, N, E);
  scat_k<<<gE, blk, 0, stream>>>(ei, ea, bBase, Off, tmp, E, N, nbuk);
  sort_k<<<nbuk, blk, 0, stream>>>(tmp, bBase, csc, offs, N);
  deg_convw_k<<<gN, blk, 0, stream>>>(offs, csc, dinv, W0, W1, W2, Wt, N);

  int gGemm = (N + 63) / 64;
  // aggregate grid: nbq node-blocks per quarter (64 nodes/block), 2 XCD
  // slots per quarter, interleaved via blockIdx&7
  int nbq  = (N + 63) / 64;
  int gAgg = ((nbq + 1) / 2) * 8;

  // layer 0 (h0 construction fused into the GEMM A-fragment load)
  gemm0_k<<<gGemm, 256, 0, stream>>>(x, Wt, dinv, B, N);
  aggregate_k<<<gAgg, blk, 0, stream>>>(offs, csc, B, dinv, b0,
                                        bng, bnb, bnm, bnv, 1, A, N, nbq);
  // layer 1
  gemm_k<<<gGemm, 256, 0, stream>>>(A, Wt + HD * HD, dinv, B, N);
  aggregate_k<<<gAgg, blk, 0, stream>>>(offs, csc, B, dinv, b1,
                                        bng, bnb, bnm, bnv, 1, A, N, nbq);
  // layer 2 (no bn/relu)
  gemm_k<<<gGemm, 256, 0, stream>>>(A, Wt + 2 * HD * HD, dinv, B, N);
  aggregate_k<<<gAgg, blk, 0, stream>>>(offs, csc, B, dinv, b2,
                                        bng, bnb, bnm, bnv, 0, A, N, nbq);

  dim3 pgrid(PCH, GD);
  pool1_k<<<pgrid, 128, 0, stream>>>(A, b32, part, N);
  mlp_k<<<GD, 128, 0, stream>>>(part, b32, mW1, mb1, mW2, mb2, out, N);
}

// Round 8
// 329.529 us; speedup vs baseline: 1.0780x; 1.0780x over previous
//
#include <hip/hip_runtime.h>
#include <hip/hip_bf16.h>
#include <stdint.h>

#define HD 128
#define GD 64
#define OUTD 16
#define PCH 32  // pool chunks per graph

typedef unsigned short u16;
typedef unsigned int u32;
typedef __attribute__((ext_vector_type(8))) short short8;
typedef __attribute__((ext_vector_type(4))) float f32x4;
typedef __attribute__((ext_vector_type(4))) unsigned short u16x4;

__device__ __forceinline__ float bf2f(u16 u) {
  union { uint32_t i; float f; } v; v.i = ((uint32_t)u) << 16; return v.f;
}
__device__ __forceinline__ u16 f2bf(float f) {
  union { __hip_bfloat16 h; u16 u; } v; v.h = __float2bfloat16(f); return v.u;
}

// exclusive scan of 256 per-thread values via LDS (Hillis-Steele).
__device__ __forceinline__ u32 excl_scan256(u32 v, u32* s, int t, u32* total) {
  s[t] = v;
  __syncthreads();
#pragma unroll
  for (int off = 1; off < 256; off <<= 1) {
    u32 x = (t >= off) ? s[t - off] : 0u;
    __syncthreads();
    s[t] += x;
    __syncthreads();
  }
  u32 incl = s[t];
  u32 tot = s[255];
  __syncthreads();
  *total = tot;
  return incl - v;
}

__device__ __forceinline__ int detect_is64(const int* ei) {
  int all0 = 1;
  for (int k = 1; k < 128; k += 2) all0 &= (ei[k] == 0);
  return all0;
}

// K1: per-block LDS histogram over col-buckets (col>>8); no global atomics.
__global__ __launch_bounds__(256)
void hist_k(const int* __restrict__ ei, const int* __restrict__ bt,
            int* __restrict__ b32, int* __restrict__ Hist, int E, int N) {
  __shared__ int h[256];
  __shared__ int s_is64;
  h[threadIdx.x] = 0;
  if (threadIdx.x == 0) s_is64 = detect_is64(ei);
  __syncthreads();
  int is64 = s_is64;
  int i = blockIdx.x * 256 + threadIdx.x;
  if (i < E) {
    int c = is64 ? ei[2 * (E + i)] : ei[E + i];
    c = (c < 0) ? 0 : (c >= N ? N - 1 : c);
    atomicAdd(&h[c >> 8], 1);              // LDS atomic
  }
  if (i < N) {
    int v = is64 ? bt[2 * i] : bt[i];
    b32[i] = (v < 0) ? 0 : (v >= GD ? GD - 1 : v);
  }
  __syncthreads();
  Hist[(size_t)blockIdx.x * 256 + threadIdx.x] = h[threadIdx.x];
}

// K2: for bucket b = blockIdx, exclusive-scan Hist[*][b] across blocks.
__global__ __launch_bounds__(256)
void scan_k(const int* __restrict__ Hist, int* __restrict__ Off,
            int* __restrict__ totals, int nblk) {
  __shared__ u32 s[256];
  int b = blockIdx.x, t = threadIdx.x;
  int chunk = (nblk + 255) >> 8;
  int i0 = t * chunk;
  int i1 = i0 + chunk; if (i1 > nblk) i1 = nblk;
  u32 part = 0;
  for (int i = i0; i < i1; ++i) part += (u32)Hist[(size_t)i * 256 + b];
  u32 tot;
  u32 run = excl_scan256(part, s, t, &tot);
  for (int i = i0; i < i1; ++i) {
    u32 h = (u32)Hist[(size_t)i * 256 + b];
    Off[(size_t)i * 256 + b] = (int)run;
    run += h;
  }
  if (t == 0) totals[b] = (int)tot;
}

// K2b: bucketBase = exclusive scan of totals; offs[N] = E.
__global__ __launch_bounds__(256)
void base_k(const int* __restrict__ totals, int* __restrict__ bucketBase,
            int* __restrict__ offs, int nbuk, int N, int E) {
  __shared__ u32 s[256];
  int t = threadIdx.x;
  u32 v = (t < nbuk) ? (u32)totals[t] : 0u;
  u32 tot;
  u32 excl = excl_scan256(v, s, t, &tot);
  bucketBase[t] = (int)excl;
  if (t == 0) offs[N] = E;
}

// K3: scatter edges into bucket-partitioned tmp; LDS cursors only.
__global__ __launch_bounds__(256)
void scat_k(const int* __restrict__ ei, const float* __restrict__ ea,
            const int* __restrict__ bucketBase, const int* __restrict__ Off,
            int2* __restrict__ tmp, int E, int N, int nbuk) {
  __shared__ u32 cur[256];
  __shared__ int s_is64;
  int t = threadIdx.x;
  if (t == 0) s_is64 = detect_is64(ei);
  cur[t] = (t < nbuk)
         ? (u32)(bucketBase[t] + Off[(size_t)blockIdx.x * 256 + t]) : 0u;
  __syncthreads();
  int is64 = s_is64;
  int i = blockIdx.x * 256 + t;
  if (i >= E) return;
  int r = is64 ? ei[2 * i] : ei[i];
  int c = is64 ? ei[2 * (E + i)] : ei[E + i];
  r = (r < 0) ? 0 : (r >= N ? N - 1 : r);
  c = (c < 0) ? 0 : (c >= N ? N - 1 : c);
  float a = ea[i];
  float w = isnan(a) ? 0.f : fabsf(a);
  u32 pos = atomicAdd(&cur[c >> 8], 1u);  // LDS atomic
  tmp[pos] = make_int2((int)(((u32)(c & 255) << 16) | (u32)r), __float_as_int(w));
}

// K4: per-bucket column sort into final csc + offs.
__global__ __launch_bounds__(256)
void sort_k(const int2* __restrict__ tmp, const int* __restrict__ bucketBase,
            int2* __restrict__ csc, int* __restrict__ offs, int N) {
  __shared__ u32 cnt[256];
  __shared__ u32 s[256];
  __shared__ u32 cur[256];
  int b = blockIdx.x, t = threadIdx.x;
  int s0 = bucketBase[b], s1 = bucketBase[b + 1];
  cnt[t] = 0;
  __syncthreads();
  for (int p = s0 + t; p < s1; p += 256) {
    u32 rc = (u32)tmp[p].x;
    atomicAdd(&cnt[rc >> 16], 1u);
  }
  __syncthreads();
  u32 tot;
  u32 excl = excl_scan256(cnt[t], s, t, &tot);
  u32 st = (u32)s0 + excl;
  int col = (b << 8) + t;
  if (col < N) offs[col] = (int)st;
  cur[t] = st;
  __syncthreads();
  for (int p = s0 + t; p < s1; p += 256) {
    int2 r = tmp[p];
    u32 rc = (u32)r.x;
    u32 pos = atomicAdd(&cur[rc >> 16], 1u);
    csc[pos] = make_int2((int)(rc & 0xFFFFu), r.y);
  }
}

// merged: dinv + weight transpose/convert
__global__ void deg_convw_k(const int* __restrict__ offs, const int2* __restrict__ csc,
                            float* __restrict__ dinv,
                            const float* __restrict__ W0, const float* __restrict__ W1,
                            const float* __restrict__ W2, u16* __restrict__ Wt, int N) {
  int i = blockIdx.x * 256 + threadIdx.x;
  if (i < 3 * HD * HD) {
    int l = i / (HD * HD);
    int r = i - l * (HD * HD);
    int n = r >> 7, k = r & 127;
    const float* W = (l == 0) ? W0 : (l == 1) ? W1 : W2;
    Wt[i] = f2bf(W[k * HD + n]);
  }
  if (i < N) {
    int p = offs[i], pe = offs[i + 1];
    float s = 0.f;
    for (; p < pe; ++p) s += __int_as_float(csc[p].y);
    dinv[i] = rsqrtf(s + 1.0f);
  }
}

// ---- aggregate one node's 8-feature slice into acc[8] (16 lanes/node).
// acc starts from self term; adds sum_in w*B[row].  f8 = feature offset.
__device__ __forceinline__ void agg_node(const int* __restrict__ offs,
                                         const int2* __restrict__ csc,
                                         const u16* __restrict__ B,
                                         int n, int f8, float* acc) {
  short8 bu = *(const short8*)(B + (size_t)n * HD + f8);
#pragma unroll
  for (int u = 0; u < 8; ++u) acc[u] = bf2f((u16)bu[u]);   // self term C[n]
  int p = offs[n], pe = offs[n + 1];
  for (; p + 7 < pe; p += 8) {
    int2 e[8];
    short8 h[8];
#pragma unroll
    for (int u = 0; u < 8; ++u) e[u] = csc[p + u];
#pragma unroll
    for (int u = 0; u < 8; ++u) h[u] = *(const short8*)(B + (size_t)e[u].x * HD + f8);
#pragma unroll
    for (int u = 0; u < 8; ++u) {
      float w = __int_as_float(e[u].y);
#pragma unroll
      for (int q = 0; q < 8; ++q) acc[q] += w * bf2f((u16)h[u][q]);
    }
  }
  for (; p + 1 < pe; p += 2) {
    int2 e0 = csc[p], e1 = csc[p + 1];
    short8 h0 = *(const short8*)(B + (size_t)e0.x * HD + f8);
    short8 h1 = *(const short8*)(B + (size_t)e1.x * HD + f8);
    float w0 = __int_as_float(e0.y), w1 = __int_as_float(e1.y);
#pragma unroll
    for (int q = 0; q < 8; ++q)
      acc[q] += w0 * bf2f((u16)h0[q]) + w1 * bf2f((u16)h1[q]);
  }
  if (p < pe) {
    int2 e0 = csc[p];
    float w0 = __int_as_float(e0.y);
    short8 h0 = *(const short8*)(B + (size_t)e0.x * HD + f8);
#pragma unroll
    for (int q = 0; q < 8; ++q) acc[q] += w0 * bf2f((u16)h0[q]);
  }
}

__device__ __forceinline__ void agg_epilogue(float* acc, int f8, float dn,
                                             const float* __restrict__ bias,
                                             const float* __restrict__ gamma,
                                             const float* __restrict__ beta,
                                             const float* __restrict__ mean,
                                             const float* __restrict__ var,
                                             int do_bn, short8* o) {
#pragma unroll
  for (int q = 0; q < 8; ++q) acc[q] = dn * acc[q] + bias[f8 + q];
  if (do_bn) {
#pragma unroll
    for (int q = 0; q < 8; ++q) {
      float s = gamma[f8 + q] * rsqrtf(var[f8 + q] + 1e-5f);
      float v = (acc[q] - mean[f8 + q]) * s + beta[f8 + q];
      acc[q] = v > 0.f ? v : 0.f;
    }
  }
#pragma unroll
  for (int q = 0; q < 8; ++q) (*o)[q] = (short)f2bf(acc[q]);
}

// ---- shared MFMA core (operands swapped: mfma(W_frag, A_frag)).
__device__ __forceinline__ void gemm_core(const u16* sw, const short8* afr,
                                          int m, int qd, int arow,
                                          const float* __restrict__ dinv,
                                          u16* __restrict__ B, int N) {
  const bool ok = (arow < N);
  const float dr = ok ? dinv[arow] : 0.f;
#pragma unroll
  for (int c = 0; c < 8; ++c) {
    f32x4 acc = {0.f, 0.f, 0.f, 0.f};
    const int n = c * 16 + m;
#pragma unroll
    for (int s = 0; s < 4; ++s) {
      short8 bfr = *(const short8*)(sw + n * 136 + 32 * s + 8 * qd);
      acc = __builtin_amdgcn_mfma_f32_16x16x32_bf16(bfr, afr[s], acc, 0, 0, 0);
    }
    if (ok) {
      u16x4 o;
#pragma unroll
      for (int r = 0; r < 4; ++r) o[r] = f2bf(dr * acc[r]);
      *(u16x4*)(B + (size_t)arow * HD + c * 16 + qd * 4) = o;
    }
  }
}

__device__ __forceinline__ void stage_w(const u16* __restrict__ Wt, u16* sw, int t) {
  const uint32_t* src = (const uint32_t*)Wt;
  uint32_t* dst = (uint32_t*)sw;
#pragma unroll
  for (int k = 0; k < 32; ++k) {
    int q = t + k * 256;
    int r = q >> 6;
    int u = q & 63;
    dst[r * 68 + u] = src[r * 64 + u];
  }
}

// layer-0 GEMM with fused h0 construction: reads x[N,64] fp32 directly.
__global__ __launch_bounds__(256)
void gemm0_k(const float* __restrict__ x, const u16* __restrict__ Wt,
             const float* __restrict__ dinv, u16* __restrict__ B, int N) {
  __shared__ u16 sw[128 * 136];
  const int t = threadIdx.x;
  stage_w(Wt, sw, t);
  __syncthreads();
  const int w = t >> 6;
  const int lane = t & 63;
  const int m = lane & 15;
  const int qd = lane >> 4;
  const int arow = blockIdx.x * 64 + w * 16 + m;
  short8 afr[4];
  if (arow < N) {
    const float* xp = x + (size_t)arow * 64;
    float v0[8], v1[8];
    *(float4*)&v0[0] = *(const float4*)(xp + 8 * qd);
    *(float4*)&v0[4] = *(const float4*)(xp + 8 * qd + 4);
    *(float4*)&v1[0] = *(const float4*)(xp + 32 + 8 * qd);
    *(float4*)&v1[4] = *(const float4*)(xp + 32 + 8 * qd + 4);
#pragma unroll
    for (int j = 0; j < 8; ++j) {
      bool n0 = isnan(v0[j]), n1 = isnan(v1[j]);
      afr[0][j] = (short)f2bf(n0 ? 0.f : v0[j]);
      afr[1][j] = (short)f2bf(n1 ? 0.f : v1[j]);
      afr[2][j] = (short)(n0 ? 0x3F80 : 0);
      afr[3][j] = (short)(n1 ? 0x3F80 : 0);
    }
  } else {
    short8 z = {0, 0, 0, 0, 0, 0, 0, 0};
#pragma unroll
    for (int s = 0; s < 4; ++s) afr[s] = z;
  }
  gemm_core(sw, afr, m, qd, arow, dinv, B, N);
}

// FUSED aggregate(layer i) -> GEMM(layer i+1) for a 64-node tile.
// Phase 1: 16 lanes/node aggregate all 128 feats of the block's 64 nodes
// (4 passes of 16 nodes) -> bf16 tile in LDS (post BN/ReLU).
// Phase 2: MFMA A-fragments straight from LDS; writes dinv-scaled B_out.
// A never touches global memory.
__global__ __launch_bounds__(256)
void agg_gemm_k(const int* __restrict__ offs, const int2* __restrict__ csc,
                const u16* __restrict__ B, const float* __restrict__ dinv,
                const float* __restrict__ bias, const float* __restrict__ gamma,
                const float* __restrict__ beta, const float* __restrict__ mean,
                const float* __restrict__ var, const u16* __restrict__ Wt,
                u16* __restrict__ Bout, int N) {
  __shared__ u16 sw[128 * 136];
  __shared__ u16 at[64 * 136];
  const int t = threadIdx.x;
  stage_w(Wt, sw, t);

  const int nl = t >> 4;          // node-lane group 0..15
  const int f8 = (t & 15) << 3;   // feature offset
#pragma unroll
  for (int it = 0; it < 4; ++it) {
    int lrow = it * 16 + nl;
    int n = blockIdx.x * 64 + lrow;
    short8 o = {0, 0, 0, 0, 0, 0, 0, 0};
    if (n < N) {
      float acc[8];
      agg_node(offs, csc, B, n, f8, acc);
      agg_epilogue(acc, f8, dinv[n], bias, gamma, beta, mean, var, 1, &o);
    }
    *(short8*)(at + lrow * 136 + f8) = o;
  }
  __syncthreads();

  const int w = t >> 6;
  const int lane = t & 63;
  const int m = lane & 15;
  const int qd = lane >> 4;
  const int lrow = w * 16 + m;
  short8 afr[4];
#pragma unroll
  for (int s = 0; s < 4; ++s)
    afr[s] = *(const short8*)(at + lrow * 136 + 32 * s + 8 * qd);
  gemm_core(sw, afr, m, qd, blockIdx.x * 64 + lrow, dinv, Bout, N);
}

// standalone aggregate (last layer, no following GEMM): writes A globally.
__global__ __launch_bounds__(256)
void aggregate_k(const int* __restrict__ offs, const int2* __restrict__ csc,
                 const u16* __restrict__ B, const float* __restrict__ dinv,
                 const float* __restrict__ bias, const float* __restrict__ gamma,
                 const float* __restrict__ beta, const float* __restrict__ mean,
                 const float* __restrict__ var, int do_bn,
                 u16* __restrict__ A, int N) {
  int tid = blockIdx.x * 256 + threadIdx.x;
  int n = tid >> 4;
  if (n >= N) return;
  int f8 = (tid & 15) << 3;
  float acc[8];
  agg_node(offs, csc, B, n, f8, acc);
  short8 o;
  agg_epilogue(acc, f8, dinv[n], bias, gamma, beta, mean, var, do_bn, &o);
  *(short8*)(A + (size_t)n * HD + f8) = o;
}

__device__ __forceinline__ int seg_lower_bound(const int* b32, int N, int b) {
  int lo = 0, hi = N;
  while (lo < hi) {
    int mid = (lo + hi) >> 1;
    if (b32[mid] < b) lo = mid + 1; else hi = mid;
  }
  return lo;
}

// two-stage mean pool, stage 1 (bf16 input); atomic-free partials.
__global__ __launch_bounds__(128)
void pool1_k(const u16* __restrict__ A, const int* __restrict__ b32,
             float* __restrict__ part, int N) {
  __shared__ int sb[2];
  int b = blockIdx.y;
  if (threadIdx.x < 2) sb[threadIdx.x] = seg_lower_bound(b32, N, b + threadIdx.x);
  __syncthreads();
  int s = sb[0], e = sb[1];
  int j = threadIdx.x;
  float a0 = 0.f, a1 = 0.f, a2 = 0.f, a3 = 0.f;
  int len = e - s;
  if (len > 0) {
    int nch = gridDim.x;
    int ch = (len + nch - 1) / nch;
    int lo = s + blockIdx.x * ch;
    int hi = lo + ch; if (hi > e) hi = e;
    int n = lo;
    for (; n + 3 < hi; n += 4) {
      a0 += bf2f(A[(size_t)(n + 0) * HD + j]);
      a1 += bf2f(A[(size_t)(n + 1) * HD + j]);
      a2 += bf2f(A[(size_t)(n + 2) * HD + j]);
      a3 += bf2f(A[(size_t)(n + 3) * HD + j]);
    }
    for (; n < hi; ++n) a0 += bf2f(A[(size_t)n * HD + j]);
  }
  part[((size_t)b * PCH + blockIdx.x) * HD + j] = (a0 + a1) + (a2 + a3);
}

// out = gelu((mean)@mW1+mb1) @ mW2 + mb2 ; mean from PCH partials
__global__ __launch_bounds__(128)
void mlp_k(const float* __restrict__ part, const int* __restrict__ b32,
           const float* __restrict__ mW1, const float* __restrict__ mb1,
           const float* __restrict__ mW2, const float* __restrict__ mb2,
           float* __restrict__ out, int N) {
  __shared__ float sg[128];
  __shared__ float st[128];
  __shared__ int sb[2];
  int b = blockIdx.x, j = threadIdx.x;
  if (j < 2) sb[j] = seg_lower_bound(b32, N, b + j);
  __syncthreads();
  int cnt = sb[1] - sb[0];
  float inv = 1.0f / (float)(cnt > 0 ? cnt : 1);
  float s0 = 0.f;
#pragma unroll
  for (int c = 0; c < PCH; ++c) s0 += part[((size_t)b * PCH + c) * HD + j];
  sg[j] = s0 * inv;
  __syncthreads();
  float s = mb1[j];
#pragma unroll 4
  for (int i = 0; i < 128; ++i) s += sg[i] * mW1[i * 128 + j];
  float ge = 0.5f * s * (1.0f + erff(s * 0.70710678118654752f));
  st[j] = ge;
  __syncthreads();
  if (j < OUTD) {
    float o = mb2[j];
#pragma unroll 4
    for (int k = 0; k < 128; ++k) o += st[k] * mW2[k * OUTD + j];
    out[b * OUTD + j] = o;
  }
}

// ---------------------------------------------------------------- launch
extern "C" void kernel_launch(void* const* d_in, const int* in_sizes, int n_in,
                              void* d_out, int out_size, void* d_ws, size_t ws_size,
                              hipStream_t stream) {
  const float* x   = (const float*)d_in[0];
  const int* ei    = (const int*)d_in[1];
  const float* ea  = (const float*)d_in[2];
  const int* bt    = (const int*)d_in[3];
  const float* W0  = (const float*)d_in[4];
  const float* b0  = (const float*)d_in[5];
  const float* W1  = (const float*)d_in[6];
  const float* b1  = (const float*)d_in[7];
  const float* W2  = (const float*)d_in[8];
  const float* b2  = (const float*)d_in[9];
  const float* bng = (const float*)d_in[10];
  const float* bnb = (const float*)d_in[11];
  const float* bnm = (const float*)d_in[12];
  const float* bnv = (const float*)d_in[13];
  const float* mW1 = (const float*)d_in[14];
  const float* mb1 = (const float*)d_in[15];
  const float* mW2 = (const float*)d_in[16];
  const float* mb2 = (const float*)d_in[17];
  float* out = (float*)d_out;

  const int N = in_sizes[0] / 64;      // 50000  (rows fit in 16 bits)
  const int E = in_sizes[2];           // 800000

  char* ws = (char*)d_ws;
  size_t NB2 = (size_t)N * HD * 2;     // bf16 feature buffer
  u16* A       = (u16*)(ws);
  u16* B       = (u16*)(ws + NB2);
  char* q      = ws + 2 * NB2;
  float* part  = (float*)q;            q += (size_t)GD * PCH * HD * 4;
  u16* Wt      = (u16*)q;              q += (size_t)3 * HD * HD * 2;
  int2* csc    = (int2*)q;             q += (size_t)E * 8;
  int2* tmp    = (int2*)q;             q += (size_t)E * 8;
  int gE  = (E + 255) / 256;
  int*   Hist  = (int*)q;              q += (size_t)gE * 256 * 4;
  int*   Off   = (int*)q;              q += (size_t)gE * 256 * 4;
  int*   totals= (int*)q;              q += 256 * 4;
  int*   bBase = (int*)q;              q += 260 * 4;
  float* dinv  = (float*)q;            q += (size_t)N * 4;
  int*   offs  = (int*)q;              q += (size_t)(N + 2) * 4;
  int*   b32   = (int*)q;              q += (size_t)N * 4;

  dim3 blk(256);
  int gN   = (N + 255) / 256;
  int nbuk = gN;                       // col buckets (col>>8)

  hist_k<<<gE, blk, 0, stream>>>(ei, bt, b32, Hist, E, N);
  scan_k<<<nbuk, blk, 0, stream>>>(Hist, Off, totals, gE);
  base_k<<<1, blk, 0, stream>>>(totals, bBase, offs, nbuk, N, E);
  scat_k<<<gE, blk, 0, stream>>>(ei, ea, bBase, Off, tmp, E, N, nbuk);
  sort_k<<<nbuk, blk, 0, stream>>>(tmp, bBase, csc, offs, N);
  deg_convw_k<<<gN, blk, 0, stream>>>(offs, csc, dinv, W0, W1, W2, Wt, N);

  int gGemm = (N + 63) / 64;
  int gAgg  = (N * 16 + 255) / 256;

  // layer 0 GEMM: C0 = dinv*(h0@W0)   (h0 built in the A-fragment load)
  gemm0_k<<<gGemm, 256, 0, stream>>>(x, Wt, dinv, B, N);
  // fused: aggregate layer0 (+BN/ReLU) -> GEMM W1 -> B
  agg_gemm_k<<<gGemm, 256, 0, stream>>>(offs, csc, B, dinv, b0,
                                        bng, bnb, bnm, bnv, Wt + HD * HD, A, N);
  // fused: aggregate layer1 (+BN/ReLU) -> GEMM W2 -> B
  agg_gemm_k<<<gGemm, 256, 0, stream>>>(offs, csc, A, dinv, b1,
                                        bng, bnb, bnm, bnv, Wt + 2 * HD * HD, B, N);
  // layer 2 aggregate (no bn/relu) -> final features A
  aggregate_k<<<gAgg, blk, 0, stream>>>(offs, csc, B, dinv, b2,
                                        bng, bnb, bnm, bnv, 0, A, N);

  dim3 pgrid(PCH, GD);
  pool1_k<<<pgrid, 128, 0, stream>>>(A, b32, part, N);
  mlp_k<<<GD, 128, 0, stream>>>(part, b32, mW1, mb1, mW2, mb2, out, N);
}

// Round 9
// 318.851 us; speedup vs baseline: 1.1142x; 1.0335x over previous
//
#include <hip/hip_runtime.h>
#include <hip/hip_bf16.h>
#include <stdint.h>

#define HD 128
#define GD 64
#define OUTD 16
#define PCH 32  // pool chunks per graph

typedef unsigned short u16;
typedef unsigned int u32;
typedef __attribute__((ext_vector_type(8))) short short8;
typedef __attribute__((ext_vector_type(4))) float f32x4;
typedef __attribute__((ext_vector_type(4))) unsigned short u16x4;

__device__ __forceinline__ float bf2f(u16 u) {
  union { uint32_t i; float f; } v; v.i = ((uint32_t)u) << 16; return v.f;
}
__device__ __forceinline__ u16 f2bf(float f) {
  union { __hip_bfloat16 h; u16 u; } v; v.h = __float2bfloat16(f); return v.u;
}

// exclusive scan of 256 per-thread values via LDS (Hillis-Steele).
__device__ __forceinline__ u32 excl_scan256(u32 v, u32* s, int t, u32* total) {
  s[t] = v;
  __syncthreads();
#pragma unroll
  for (int off = 1; off < 256; off <<= 1) {
    u32 x = (t >= off) ? s[t - off] : 0u;
    __syncthreads();
    s[t] += x;
    __syncthreads();
  }
  u32 incl = s[t];
  u32 tot = s[255];
  __syncthreads();
  *total = tot;
  return incl - v;
}

__device__ __forceinline__ int detect_is64(const int* ei) {
  int all0 = 1;
  for (int k = 1; k < 128; k += 2) all0 &= (ei[k] == 0);
  return all0;
}

// K1: per-block LDS histogram over col-buckets (col>>8); no global atomics.
// Fused: batch convert, W transpose/convert (first 192 blocks), offs[N]=E.
__global__ __launch_bounds__(256)
void hist_k(const int* __restrict__ ei, const int* __restrict__ bt,
            int* __restrict__ b32, int* __restrict__ Hist,
            const float* __restrict__ W0, const float* __restrict__ W1,
            const float* __restrict__ W2, u16* __restrict__ Wt,
            int* __restrict__ offs, int E, int N) {
  __shared__ int h[256];
  __shared__ int s_is64;
  h[threadIdx.x] = 0;
  if (threadIdx.x == 0) s_is64 = detect_is64(ei);
  __syncthreads();
  int is64 = s_is64;
  int i = blockIdx.x * 256 + threadIdx.x;
  if (i == 0) offs[N] = E;
  if (i < E) {
    int c = is64 ? ei[2 * (E + i)] : ei[E + i];
    c = (c < 0) ? 0 : (c >= N ? N - 1 : c);
    atomicAdd(&h[c >> 8], 1);              // LDS atomic
  }
  if (i < N) {
    int v = is64 ? bt[2 * i] : bt[i];
    b32[i] = (v < 0) ? 0 : (v >= GD ? GD - 1 : v);
  }
  if (i < 3 * HD * HD) {
    int l = i / (HD * HD);
    int r = i - l * (HD * HD);
    int n = r >> 7, k = r & 127;
    const float* W = (l == 0) ? W0 : (l == 1) ? W1 : W2;
    Wt[i] = f2bf(W[k * HD + n]);
  }
  __syncthreads();
  Hist[(size_t)blockIdx.x * 256 + threadIdx.x] = h[threadIdx.x];
}

// K2: for bucket b = blockIdx, exclusive-scan Hist[*][b] across blocks.
__global__ __launch_bounds__(256)
void scan_k(const int* __restrict__ Hist, int* __restrict__ Off,
            int* __restrict__ totals, int nblk) {
  __shared__ u32 s[256];
  int b = blockIdx.x, t = threadIdx.x;
  int chunk = (nblk + 255) >> 8;
  int i0 = t * chunk;
  int i1 = i0 + chunk; if (i1 > nblk) i1 = nblk;
  u32 part = 0;
  for (int i = i0; i < i1; ++i) part += (u32)Hist[(size_t)i * 256 + b];
  u32 tot;
  u32 run = excl_scan256(part, s, t, &tot);
  for (int i = i0; i < i1; ++i) {
    u32 h = (u32)Hist[(size_t)i * 256 + b];
    Off[(size_t)i * 256 + b] = (int)run;
    run += h;
  }
  if (t == 0) totals[b] = (int)tot;
}

// K3: scatter edges into bucket-partitioned tmp; LDS cursors only.
// Bucket bases computed inline from totals (in-LDS scan).
__global__ __launch_bounds__(256)
void scat_k(const int* __restrict__ ei, const float* __restrict__ ea,
            const int* __restrict__ totals, const int* __restrict__ Off,
            int2* __restrict__ tmp, int E, int N, int nbuk) {
  __shared__ u32 s[256];
  __shared__ u32 cur[256];
  __shared__ int s_is64;
  int t = threadIdx.x;
  if (t == 0) s_is64 = detect_is64(ei);
  u32 v = (t < nbuk) ? (u32)totals[t] : 0u;
  u32 tot;
  u32 base = excl_scan256(v, s, t, &tot);
  cur[t] = (t < nbuk)
         ? (base + (u32)Off[(size_t)blockIdx.x * 256 + t]) : 0u;
  __syncthreads();
  int is64 = s_is64;
  int i = blockIdx.x * 256 + t;
  if (i >= E) return;
  int r = is64 ? ei[2 * i] : ei[i];
  int c = is64 ? ei[2 * (E + i)] : ei[E + i];
  r = (r < 0) ? 0 : (r >= N ? N - 1 : r);
  c = (c < 0) ? 0 : (c >= N ? N - 1 : c);
  float a = ea[i];
  float w = isnan(a) ? 0.f : fabsf(a);
  u32 pos = atomicAdd(&cur[c >> 8], 1u);  // LDS atomic
  tmp[pos] = make_int2((int)(((u32)(c & 255) << 16) | (u32)r), __float_as_int(w));
}

// K4: per-bucket column sort into final csc + offs; bucket base inline.
// Fused: dinv[col] = rsqrt(colsum(|w|)+1) via re-read of the block's
// just-written (L2-hot) csc range.
__global__ __launch_bounds__(256)
void sort_k(const int2* __restrict__ tmp, const int* __restrict__ totals,
            int2* __restrict__ csc, int* __restrict__ offs,
            float* __restrict__ dinv, int N, int nbuk) {
  __shared__ u32 cnt[256];
  __shared__ u32 s[256];
  __shared__ u32 cur[256];
  __shared__ u32 bb[256];
  int b = blockIdx.x, t = threadIdx.x;
  u32 v = (t < nbuk) ? (u32)totals[t] : 0u;
  u32 tot;
  u32 base = excl_scan256(v, s, t, &tot);
  bb[t] = base;
  cnt[t] = 0;
  __syncthreads();
  int s0 = (int)bb[b];
  int s1 = s0 + totals[b];
  for (int p = s0 + t; p < s1; p += 256) {
    u32 rc = (u32)tmp[p].x;
    atomicAdd(&cnt[rc >> 16], 1u);
  }
  __syncthreads();
  u32 myc = cnt[t];
  u32 excl = excl_scan256(myc, s, t, &tot);
  u32 st = (u32)s0 + excl;
  int col = (b << 8) + t;
  if (col < N) offs[col] = (int)st;
  cur[t] = st;
  __syncthreads();
  for (int p = s0 + t; p < s1; p += 256) {
    int2 r = tmp[p];
    u32 rc = (u32)r.x;
    u32 pos = atomicAdd(&cur[rc >> 16], 1u);
    csc[pos] = make_int2((int)(rc & 0xFFFFu), r.y);
  }
  __syncthreads();
  if (col < N) {
    float ssum = 0.f;
    for (u32 p = st; p < st + myc; ++p) ssum += __int_as_float(csc[p].y);
    dinv[col] = rsqrtf(ssum + 1.0f);
  }
}

// ---- aggregate one node's 8-feature slice into acc[8] (16 lanes/node).
__device__ __forceinline__ void agg_node(const int* __restrict__ offs,
                                         const int2* __restrict__ csc,
                                         const u16* __restrict__ B,
                                         int n, int f8, float* acc) {
  short8 bu = *(const short8*)(B + (size_t)n * HD + f8);
#pragma unroll
  for (int u = 0; u < 8; ++u) acc[u] = bf2f((u16)bu[u]);   // self term C[n]
  int p = offs[n], pe = offs[n + 1];
  for (; p + 7 < pe; p += 8) {
    int2 e[8];
    short8 h[8];
#pragma unroll
    for (int u = 0; u < 8; ++u) e[u] = csc[p + u];
#pragma unroll
    for (int u = 0; u < 8; ++u) h[u] = *(const short8*)(B + (size_t)e[u].x * HD + f8);
#pragma unroll
    for (int u = 0; u < 8; ++u) {
      float w = __int_as_float(e[u].y);
#pragma unroll
      for (int q = 0; q < 8; ++q) acc[q] += w * bf2f((u16)h[u][q]);
    }
  }
  for (; p + 1 < pe; p += 2) {
    int2 e0 = csc[p], e1 = csc[p + 1];
    short8 h0 = *(const short8*)(B + (size_t)e0.x * HD + f8);
    short8 h1 = *(const short8*)(B + (size_t)e1.x * HD + f8);
    float w0 = __int_as_float(e0.y), w1 = __int_as_float(e1.y);
#pragma unroll
    for (int q = 0; q < 8; ++q)
      acc[q] += w0 * bf2f((u16)h0[q]) + w1 * bf2f((u16)h1[q]);
  }
  if (p < pe) {
    int2 e0 = csc[p];
    float w0 = __int_as_float(e0.y);
    short8 h0 = *(const short8*)(B + (size_t)e0.x * HD + f8);
#pragma unroll
    for (int q = 0; q < 8; ++q) acc[q] += w0 * bf2f((u16)h0[q]);
  }
}

__device__ __forceinline__ void agg_epilogue(float* acc, int f8, float dn,
                                             const float* __restrict__ bias,
                                             const float* __restrict__ gamma,
                                             const float* __restrict__ beta,
                                             const float* __restrict__ mean,
                                             const float* __restrict__ var,
                                             int do_bn, short8* o) {
#pragma unroll
  for (int q = 0; q < 8; ++q) acc[q] = dn * acc[q] + bias[f8 + q];
  if (do_bn) {
#pragma unroll
    for (int q = 0; q < 8; ++q) {
      float s = gamma[f8 + q] * rsqrtf(var[f8 + q] + 1e-5f);
      float v = (acc[q] - mean[f8 + q]) * s + beta[f8 + q];
      acc[q] = v > 0.f ? v : 0.f;
    }
  }
#pragma unroll
  for (int q = 0; q < 8; ++q) (*o)[q] = (short)f2bf(acc[q]);
}

// unsplit aggregate: 16 lanes/node, full 256B/edge gather, csc streamed once.
// No LDS -> max occupancy (latency-bound gather needs waves, round-8 lesson).
__global__ __launch_bounds__(256)
void aggregate_k(const int* __restrict__ offs, const int2* __restrict__ csc,
                 const u16* __restrict__ B, const float* __restrict__ dinv,
                 const float* __restrict__ bias, const float* __restrict__ gamma,
                 const float* __restrict__ beta, const float* __restrict__ mean,
                 const float* __restrict__ var, int do_bn,
                 u16* __restrict__ A, int N) {
  int tid = blockIdx.x * 256 + threadIdx.x;
  int n = tid >> 4;
  if (n >= N) return;
  int f8 = (tid & 15) << 3;
  float acc[8];
  agg_node(offs, csc, B, n, f8, acc);
  short8 o;
  agg_epilogue(acc, f8, dinv[n], bias, gamma, beta, mean, var, do_bn, &o);
  *(short8*)(A + (size_t)n * HD + f8) = o;
}

// ---- shared MFMA core (operands swapped: mfma(W_frag, A_frag)).
__device__ __forceinline__ void gemm_core(const u16* sw, const short8* afr,
                                          int m, int qd, int arow,
                                          const float* __restrict__ dinv,
                                          u16* __restrict__ B, int N) {
  const bool ok = (arow < N);
  const float dr = ok ? dinv[arow] : 0.f;
#pragma unroll
  for (int c = 0; c < 8; ++c) {
    f32x4 acc = {0.f, 0.f, 0.f, 0.f};
    const int n = c * 16 + m;
#pragma unroll
    for (int s = 0; s < 4; ++s) {
      short8 bfr = *(const short8*)(sw + n * 136 + 32 * s + 8 * qd);
      acc = __builtin_amdgcn_mfma_f32_16x16x32_bf16(bfr, afr[s], acc, 0, 0, 0);
    }
    if (ok) {
      u16x4 o;
#pragma unroll
      for (int r = 0; r < 4; ++r) o[r] = f2bf(dr * acc[r]);
      *(u16x4*)(B + (size_t)arow * HD + c * 16 + qd * 4) = o;
    }
  }
}

__device__ __forceinline__ void stage_w(const u16* __restrict__ Wt, u16* sw, int t) {
  const uint32_t* src = (const uint32_t*)Wt;
  uint32_t* dst = (uint32_t*)sw;
#pragma unroll
  for (int k = 0; k < 32; ++k) {
    int q = t + k * 256;
    int r = q >> 6;
    int u = q & 63;
    dst[r * 68 + u] = src[r * 64 + u];
  }
}

// layer-0 GEMM with fused h0 construction: reads x[N,64] fp32 directly.
__global__ __launch_bounds__(256)
void gemm0_k(const float* __restrict__ x, const u16* __restrict__ Wt,
             const float* __restrict__ dinv, u16* __restrict__ B, int N) {
  __shared__ u16 sw[128 * 136];
  const int t = threadIdx.x;
  stage_w(Wt, sw, t);
  __syncthreads();
  const int w = t >> 6;
  const int lane = t & 63;
  const int m = lane & 15;
  const int qd = lane >> 4;
  const int arow = blockIdx.x * 64 + w * 16 + m;
  short8 afr[4];
  if (arow < N) {
    const float* xp = x + (size_t)arow * 64;
    float v0[8], v1[8];
    *(float4*)&v0[0] = *(const float4*)(xp + 8 * qd);
    *(float4*)&v0[4] = *(const float4*)(xp + 8 * qd + 4);
    *(float4*)&v1[0] = *(const float4*)(xp + 32 + 8 * qd);
    *(float4*)&v1[4] = *(const float4*)(xp + 32 + 8 * qd + 4);
#pragma unroll
    for (int j = 0; j < 8; ++j) {
      bool n0 = isnan(v0[j]), n1 = isnan(v1[j]);
      afr[0][j] = (short)f2bf(n0 ? 0.f : v0[j]);
      afr[1][j] = (short)f2bf(n1 ? 0.f : v1[j]);
      afr[2][j] = (short)(n0 ? 0x3F80 : 0);
      afr[3][j] = (short)(n1 ? 0x3F80 : 0);
    }
  } else {
    short8 z = {0, 0, 0, 0, 0, 0, 0, 0};
#pragma unroll
    for (int s = 0; s < 4; ++s) afr[s] = z;
  }
  gemm_core(sw, afr, m, qd, arow, dinv, B, N);
}

// generic GEMM: B = dinv-scaled rows of (A @ W), A bf16
__global__ __launch_bounds__(256)
void gemm_k(const u16* __restrict__ A, const u16* __restrict__ Wt,
            const float* __restrict__ dinv, u16* __restrict__ B, int N) {
  __shared__ u16 sw[128 * 136];
  const int t = threadIdx.x;
  stage_w(Wt, sw, t);
  __syncthreads();
  const int w = t >> 6;
  const int lane = t & 63;
  const int m = lane & 15;
  const int qd = lane >> 4;
  const int arow = blockIdx.x * 64 + w * 16 + m;
  short8 afr[4];
  if (arow < N) {
    const short8* ap = (const short8*)(A + (size_t)arow * HD);
#pragma unroll
    for (int s = 0; s < 4; ++s) afr[s] = ap[4 * s + qd];
  } else {
    short8 z = {0, 0, 0, 0, 0, 0, 0, 0};
#pragma unroll
    for (int s = 0; s < 4; ++s) afr[s] = z;
  }
  gemm_core(sw, afr, m, qd, arow, dinv, B, N);
}

__device__ __forceinline__ int seg_lower_bound(const int* b32, int N, int b) {
  int lo = 0, hi = N;
  while (lo < hi) {
    int mid = (lo + hi) >> 1;
    if (b32[mid] < b) lo = mid + 1; else hi = mid;
  }
  return lo;
}

// two-stage mean pool, stage 1 (bf16 input); atomic-free partials.
__global__ __launch_bounds__(128)
void pool1_k(const u16* __restrict__ A, const int* __restrict__ b32,
             float* __restrict__ part, int N) {
  __shared__ int sb[2];
  int b = blockIdx.y;
  if (threadIdx.x < 2) sb[threadIdx.x] = seg_lower_bound(b32, N, b + threadIdx.x);
  __syncthreads();
  int s = sb[0], e = sb[1];
  int j = threadIdx.x;
  float a0 = 0.f, a1 = 0.f, a2 = 0.f, a3 = 0.f;
  int len = e - s;
  if (len > 0) {
    int nch = gridDim.x;
    int ch = (len + nch - 1) / nch;
    int lo = s + blockIdx.x * ch;
    int hi = lo + ch; if (hi > e) hi = e;
    int n = lo;
    for (; n + 3 < hi; n += 4) {
      a0 += bf2f(A[(size_t)(n + 0) * HD + j]);
      a1 += bf2f(A[(size_t)(n + 1) * HD + j]);
      a2 += bf2f(A[(size_t)(n + 2) * HD + j]);
      a3 += bf2f(A[(size_t)(n + 3) * HD + j]);
    }
    for (; n < hi; ++n) a0 += bf2f(A[(size_t)n * HD + j]);
  }
  part[((size_t)b * PCH + blockIdx.x) * HD + j] = (a0 + a1) + (a2 + a3);
}

// out = gelu((mean)@mW1+mb1) @ mW2 + mb2 ; mean from PCH partials
__global__ __launch_bounds__(128)
void mlp_k(const float* __restrict__ part, const int* __restrict__ b32,
           const float* __restrict__ mW1, const float* __restrict__ mb1,
           const float* __restrict__ mW2, const float* __restrict__ mb2,
           float* __restrict__ out, int N) {
  __shared__ float sg[128];
  __shared__ float st[128];
  __shared__ int sb[2];
  int b = blockIdx.x, j = threadIdx.x;
  if (j < 2) sb[j] = seg_lower_bound(b32, N, b + j);
  __syncthreads();
  int cnt = sb[1] - sb[0];
  float inv = 1.0f / (float)(cnt > 0 ? cnt : 1);
  float s0 = 0.f;
#pragma unroll
  for (int c = 0; c < PCH; ++c) s0 += part[((size_t)b * PCH + c) * HD + j];
  sg[j] = s0 * inv;
  __syncthreads();
  float s = mb1[j];
#pragma unroll 4
  for (int i = 0; i < 128; ++i) s += sg[i] * mW1[i * 128 + j];
  float ge = 0.5f * s * (1.0f + erff(s * 0.70710678118654752f));
  st[j] = ge;
  __syncthreads();
  if (j < OUTD) {
    float o = mb2[j];
#pragma unroll 4
    for (int k = 0; k < 128; ++k) o += st[k] * mW2[k * OUTD + j];
    out[b * OUTD + j] = o;
  }
}

// ---------------------------------------------------------------- launch
extern "C" void kernel_launch(void* const* d_in, const int* in_sizes, int n_in,
                              void* d_out, int out_size, void* d_ws, size_t ws_size,
                              hipStream_t stream) {
  const float* x   = (const float*)d_in[0];
  const int* ei    = (const int*)d_in[1];
  const float* ea  = (const float*)d_in[2];
  const int* bt    = (const int*)d_in[3];
  const float* W0  = (const float*)d_in[4];
  const float* b0  = (const float*)d_in[5];
  const float* W1  = (const float*)d_in[6];
  const float* b1  = (const float*)d_in[7];
  const float* W2  = (const float*)d_in[8];
  const float* b2  = (const float*)d_in[9];
  const float* bng = (const float*)d_in[10];
  const float* bnb = (const float*)d_in[11];
  const float* bnm = (const float*)d_in[12];
  const float* bnv = (const float*)d_in[13];
  const float* mW1 = (const float*)d_in[14];
  const float* mb1 = (const float*)d_in[15];
  const float* mW2 = (const float*)d_in[16];
  const float* mb2 = (const float*)d_in[17];
  float* out = (float*)d_out;

  const int N = in_sizes[0] / 64;      // 50000  (rows fit in 16 bits)
  const int E = in_sizes[2];           // 800000

  char* ws = (char*)d_ws;
  size_t NB2 = (size_t)N * HD * 2;     // bf16 feature buffer
  u16* A       = (u16*)(ws);
  u16* B       = (u16*)(ws + NB2);
  char* q      = ws + 2 * NB2;
  float* part  = (float*)q;            q += (size_t)GD * PCH * HD * 4;
  u16* Wt      = (u16*)q;              q += (size_t)3 * HD * HD * 2;
  int2* csc    = (int2*)q;             q += (size_t)E * 8;
  int2* tmp    = (int2*)q;             q += (size_t)E * 8;
  int gE  = (E + 255) / 256;
  int*   Hist  = (int*)q;              q += (size_t)gE * 256 * 4;
  int*   Off   = (int*)q;              q += (size_t)gE * 256 * 4;
  int*   totals= (int*)q;              q += 256 * 4;
  float* dinv  = (float*)q;            q += (size_t)N * 4;
  int*   offs  = (int*)q;              q += (size_t)(N + 2) * 4;
  int*   b32   = (int*)q;              q += (size_t)N * 4;

  dim3 blk(256);
  int gN   = (N + 255) / 256;
  int nbuk = gN;                       // col buckets (col>>8)

  hist_k<<<gE, blk, 0, stream>>>(ei, bt, b32, Hist, W0, W1, W2, Wt, offs, E, N);
  scan_k<<<nbuk, blk, 0, stream>>>(Hist, Off, totals, gE);
  scat_k<<<gE, blk, 0, stream>>>(ei, ea, totals, Off, tmp, E, N, nbuk);
  sort_k<<<nbuk, blk, 0, stream>>>(tmp, totals, csc, offs, dinv, N, nbuk);

  int gGemm = (N + 63) / 64;
  int gAgg  = (N * 16 + 255) / 256;

  // layer 0 GEMM: C0 = dinv*(h0@W0)   (h0 built in the A-fragment load)
  gemm0_k<<<gGemm, 256, 0, stream>>>(x, Wt, dinv, B, N);
  aggregate_k<<<gAgg, blk, 0, stream>>>(offs, csc, B, dinv, b0,
                                        bng, bnb, bnm, bnv, 1, A, N);
  // layer 1
  gemm_k<<<gGemm, 256, 0, stream>>>(A, Wt + HD * HD, dinv, B, N);
  aggregate_k<<<gAgg, blk, 0, stream>>>(offs, csc, B, dinv, b1,
                                        bng, bnb, bnm, bnv, 1, A, N);
  // layer 2 (no bn/relu)
  gemm_k<<<gGemm, 256, 0, stream>>>(A, Wt + 2 * HD * HD, dinv, B, N);
  aggregate_k<<<gAgg, blk, 0, stream>>>(offs, csc, B, dinv, b2,
                                        bng, bnb, bnm, bnv, 0, A, N);

  dim3 pgrid(PCH, GD);
  pool1_k<<<pgrid, 128, 0, stream>>>(A, b32, part, N);
  mlp_k<<<GD, 128, 0, stream>>>(part, b32, mW1, mb1, mW2, mb2, out, N);
}

// Round 10
// 308.253 us; speedup vs baseline: 1.1525x; 1.0344x over previous
//
#include <hip/hip_runtime.h>
#include <hip/hip_bf16.h>
#include <stdint.h>

#define HD 128
#define GD 64
#define OUTD 16
#define PCH 32  // pool chunks per graph

typedef unsigned short u16;
typedef unsigned int u32;
typedef __attribute__((ext_vector_type(8))) short short8;
typedef __attribute__((ext_vector_type(4))) float f32x4;
typedef __attribute__((ext_vector_type(4))) unsigned short u16x4;

__device__ __forceinline__ float bf2f(u16 u) {
  union { uint32_t i; float f; } v; v.i = ((uint32_t)u) << 16; return v.f;
}
__device__ __forceinline__ u16 f2bf(float f) {
  union { __hip_bfloat16 h; u16 u; } v; v.h = __float2bfloat16(f); return v.u;
}

// exclusive scan of 256 per-thread values via LDS (Hillis-Steele).
__device__ __forceinline__ u32 excl_scan256(u32 v, u32* s, int t, u32* total) {
  s[t] = v;
  __syncthreads();
#pragma unroll
  for (int off = 1; off < 256; off <<= 1) {
    u32 x = (t >= off) ? s[t - off] : 0u;
    __syncthreads();
    s[t] += x;
    __syncthreads();
  }
  u32 incl = s[t];
  u32 tot = s[255];
  __syncthreads();
  *total = tot;
  return incl - v;
}

__device__ __forceinline__ int detect_is64(const int* ei) {
  int all0 = 1;
  for (int k = 1; k < 128; k += 2) all0 &= (ei[k] == 0);
  return all0;
}

// K1: per-block LDS histogram over col-buckets (col>>8); no global atomics.
// Fused: batch convert, W transpose/convert (first 192 blocks), offs[N]=E.
__global__ __launch_bounds__(256)
void hist_k(const int* __restrict__ ei, const int* __restrict__ bt,
            int* __restrict__ b32, int* __restrict__ Hist,
            const float* __restrict__ W0, const float* __restrict__ W1,
            const float* __restrict__ W2, u16* __restrict__ Wt,
            int* __restrict__ offs, int E, int N) {
  __shared__ int h[256];
  __shared__ int s_is64;
  h[threadIdx.x] = 0;
  if (threadIdx.x == 0) s_is64 = detect_is64(ei);
  __syncthreads();
  int is64 = s_is64;
  int i = blockIdx.x * 256 + threadIdx.x;
  if (i == 0) offs[N] = E;
  if (i < E) {
    int c = is64 ? ei[2 * (E + i)] : ei[E + i];
    c = (c < 0) ? 0 : (c >= N ? N - 1 : c);
    atomicAdd(&h[c >> 8], 1);              // LDS atomic
  }
  if (i < N) {
    int v = is64 ? bt[2 * i] : bt[i];
    b32[i] = (v < 0) ? 0 : (v >= GD ? GD - 1 : v);
  }
  if (i < 3 * HD * HD) {
    int l = i / (HD * HD);
    int r = i - l * (HD * HD);
    int n = r >> 7, k = r & 127;
    const float* W = (l == 0) ? W0 : (l == 1) ? W1 : W2;
    Wt[i] = f2bf(W[k * HD + n]);
  }
  __syncthreads();
  Hist[(size_t)blockIdx.x * 256 + threadIdx.x] = h[threadIdx.x];
}

// K2: for bucket b = blockIdx, exclusive-scan Hist[*][b] across blocks.
__global__ __launch_bounds__(256)
void scan_k(const int* __restrict__ Hist, int* __restrict__ Off,
            int* __restrict__ totals, int nblk) {
  __shared__ u32 s[256];
  int b = blockIdx.x, t = threadIdx.x;
  int chunk = (nblk + 255) >> 8;
  int i0 = t * chunk;
  int i1 = i0 + chunk; if (i1 > nblk) i1 = nblk;
  u32 part = 0;
  for (int i = i0; i < i1; ++i) part += (u32)Hist[(size_t)i * 256 + b];
  u32 tot;
  u32 run = excl_scan256(part, s, t, &tot);
  for (int i = i0; i < i1; ++i) {
    u32 h = (u32)Hist[(size_t)i * 256 + b];
    Off[(size_t)i * 256 + b] = (int)run;
    run += h;
  }
  if (t == 0) totals[b] = (int)tot;
}

// K3: scatter edges into bucket-partitioned tmp; LDS cursors only.
// Bucket bases computed inline from totals (in-LDS scan).
__global__ __launch_bounds__(256)
void scat_k(const int* __restrict__ ei, const float* __restrict__ ea,
            const int* __restrict__ totals, const int* __restrict__ Off,
            int2* __restrict__ tmp, int E, int N, int nbuk) {
  __shared__ u32 s[256];
  __shared__ u32 cur[256];
  __shared__ int s_is64;
  int t = threadIdx.x;
  if (t == 0) s_is64 = detect_is64(ei);
  u32 v = (t < nbuk) ? (u32)totals[t] : 0u;
  u32 tot;
  u32 base = excl_scan256(v, s, t, &tot);
  cur[t] = (t < nbuk)
         ? (base + (u32)Off[(size_t)blockIdx.x * 256 + t]) : 0u;
  __syncthreads();
  int is64 = s_is64;
  int i = blockIdx.x * 256 + t;
  if (i >= E) return;
  int r = is64 ? ei[2 * i] : ei[i];
  int c = is64 ? ei[2 * (E + i)] : ei[E + i];
  r = (r < 0) ? 0 : (r >= N ? N - 1 : r);
  c = (c < 0) ? 0 : (c >= N ? N - 1 : c);
  float a = ea[i];
  float w = isnan(a) ? 0.f : fabsf(a);
  u32 pos = atomicAdd(&cur[c >> 8], 1u);  // LDS atomic
  tmp[pos] = make_int2((int)(((u32)(c & 255) << 16) | (u32)r), __float_as_int(w));
}

// K4: per-bucket column sort into final csc + offs; bucket base inline.
// Fused: dinv[col] = rsqrt(colsum(|w|)+1) via re-read of the block's
// just-written (L2-hot) csc range.
__global__ __launch_bounds__(256)
void sort_k(const int2* __restrict__ tmp, const int* __restrict__ totals,
            int2* __restrict__ csc, int* __restrict__ offs,
            float* __restrict__ dinv, int N, int nbuk) {
  __shared__ u32 cnt[256];
  __shared__ u32 s[256];
  __shared__ u32 cur[256];
  __shared__ u32 bb[256];
  int b = blockIdx.x, t = threadIdx.x;
  u32 v = (t < nbuk) ? (u32)totals[t] : 0u;
  u32 tot;
  u32 base = excl_scan256(v, s, t, &tot);
  bb[t] = base;
  cnt[t] = 0;
  __syncthreads();
  int s0 = (int)bb[b];
  int s1 = s0 + totals[b];
  for (int p = s0 + t; p < s1; p += 256) {
    u32 rc = (u32)tmp[p].x;
    atomicAdd(&cnt[rc >> 16], 1u);
  }
  __syncthreads();
  u32 myc = cnt[t];
  u32 excl = excl_scan256(myc, s, t, &tot);
  u32 st = (u32)s0 + excl;
  int col = (b << 8) + t;
  if (col < N) offs[col] = (int)st;
  cur[t] = st;
  __syncthreads();
  for (int p = s0 + t; p < s1; p += 256) {
    int2 r = tmp[p];
    u32 rc = (u32)r.x;
    u32 pos = atomicAdd(&cur[rc >> 16], 1u);
    csc[pos] = make_int2((int)(rc & 0xFFFFu), r.y);
  }
  __syncthreads();
  if (col < N) {
    float ssum = 0.f;
    for (u32 p = st; p < st + myc; ++p) ssum += __int_as_float(csc[p].y);
    dinv[col] = rsqrtf(ssum + 1.0f);
  }
}

// ---- aggregate one node's 8-feature slice into acc[8].
__device__ __forceinline__ void agg_node(const int* __restrict__ offs,
                                         const int2* __restrict__ csc,
                                         const u16* __restrict__ B,
                                         int n, int f8, float* acc) {
  short8 bu = *(const short8*)(B + (size_t)n * HD + f8);
#pragma unroll
  for (int u = 0; u < 8; ++u) acc[u] = bf2f((u16)bu[u]);   // self term C[n]
  int p = offs[n], pe = offs[n + 1];
  for (; p + 7 < pe; p += 8) {
    int2 e[8];
    short8 h[8];
#pragma unroll
    for (int u = 0; u < 8; ++u) e[u] = csc[p + u];
#pragma unroll
    for (int u = 0; u < 8; ++u) h[u] = *(const short8*)(B + (size_t)e[u].x * HD + f8);
#pragma unroll
    for (int u = 0; u < 8; ++u) {
      float w = __int_as_float(e[u].y);
#pragma unroll
      for (int q = 0; q < 8; ++q) acc[q] += w * bf2f((u16)h[u][q]);
    }
  }
  for (; p + 1 < pe; p += 2) {
    int2 e0 = csc[p], e1 = csc[p + 1];
    short8 h0 = *(const short8*)(B + (size_t)e0.x * HD + f8);
    short8 h1 = *(const short8*)(B + (size_t)e1.x * HD + f8);
    float w0 = __int_as_float(e0.y), w1 = __int_as_float(e1.y);
#pragma unroll
    for (int q = 0; q < 8; ++q)
      acc[q] += w0 * bf2f((u16)h0[q]) + w1 * bf2f((u16)h1[q]);
  }
  if (p < pe) {
    int2 e0 = csc[p];
    float w0 = __int_as_float(e0.y);
    short8 h0 = *(const short8*)(B + (size_t)e0.x * HD + f8);
#pragma unroll
    for (int q = 0; q < 8; ++q) acc[q] += w0 * bf2f((u16)h0[q]);
  }
}

__device__ __forceinline__ void agg_epilogue(float* acc, int f8, float dn,
                                             const float* __restrict__ bias,
                                             const float* __restrict__ gamma,
                                             const float* __restrict__ beta,
                                             const float* __restrict__ mean,
                                             const float* __restrict__ var,
                                             int do_bn, short8* o) {
#pragma unroll
  for (int q = 0; q < 8; ++q) acc[q] = dn * acc[q] + bias[f8 + q];
  if (do_bn) {
#pragma unroll
    for (int q = 0; q < 8; ++q) {
      float s = gamma[f8 + q] * rsqrtf(var[f8 + q] + 1e-5f);
      float v = (acc[q] - mean[f8 + q]) * s + beta[f8 + q];
      acc[q] = v > 0.f ? v : 0.f;
    }
  }
#pragma unroll
  for (int q = 0; q < 8; ++q) (*o)[q] = (short)f2bf(acc[q]);
}

// Fused: A[n] = BN?ReLU( dinv[n]*(C[n] + sum_in w*C[row]) + bias )
// Feature-HALF split with XCD affinity (proven best: r5=310 vs unsplit
// r9=318.9 vs quarter r7=355): half 0 -> XCD slots 0-3, half 1 -> slots
// 4-7 via blockIdx&7 round-robin.  8 lanes/node, 16B gathers, 6.4MB/pass
// working set.  No LDS -> max occupancy (r8 lesson).
__global__ __launch_bounds__(256)
void aggregate_k(const int* __restrict__ offs, const int2* __restrict__ csc,
                 const u16* __restrict__ B, const float* __restrict__ dinv,
                 const float* __restrict__ bias, const float* __restrict__ gamma,
                 const float* __restrict__ beta, const float* __restrict__ mean,
                 const float* __restrict__ var, int do_bn,
                 u16* __restrict__ A, int N, int nbh) {
  int b = blockIdx.x;
  int half = (b >> 2) & 1;
  int j = (b & 3) | ((b >> 3) << 2);    // node-block index within half
  if (j >= nbh) return;
  int n = j * 32 + (threadIdx.x >> 3);
  if (n >= N) return;
  int f8 = ((threadIdx.x & 7) << 3) + (half << 6);
  float acc[8];
  agg_node(offs, csc, B, n, f8, acc);
  short8 o;
  agg_epilogue(acc, f8, dinv[n], bias, gamma, beta, mean, var, do_bn, &o);
  *(short8*)(A + (size_t)n * HD + f8) = o;
}

// ---- shared MFMA core (operands swapped: mfma(W_frag, A_frag)).
__device__ __forceinline__ void gemm_core(const u16* sw, const short8* afr,
                                          int m, int qd, int arow,
                                          const float* __restrict__ dinv,
                                          u16* __restrict__ B, int N) {
  const bool ok = (arow < N);
  const float dr = ok ? dinv[arow] : 0.f;
#pragma unroll
  for (int c = 0; c < 8; ++c) {
    f32x4 acc = {0.f, 0.f, 0.f, 0.f};
    const int n = c * 16 + m;
#pragma unroll
    for (int s = 0; s < 4; ++s) {
      short8 bfr = *(const short8*)(sw + n * 136 + 32 * s + 8 * qd);
      acc = __builtin_amdgcn_mfma_f32_16x16x32_bf16(bfr, afr[s], acc, 0, 0, 0);
    }
    if (ok) {
      u16x4 o;
#pragma unroll
      for (int r = 0; r < 4; ++r) o[r] = f2bf(dr * acc[r]);
      *(u16x4*)(B + (size_t)arow * HD + c * 16 + qd * 4) = o;
    }
  }
}

__device__ __forceinline__ void stage_w(const u16* __restrict__ Wt, u16* sw, int t) {
  const uint32_t* src = (const uint32_t*)Wt;
  uint32_t* dst = (uint32_t*)sw;
#pragma unroll
  for (int k = 0; k < 32; ++k) {
    int q = t + k * 256;
    int r = q >> 6;
    int u = q & 63;
    dst[r * 68 + u] = src[r * 64 + u];
  }
}

// layer-0 GEMM with fused h0 construction: reads x[N,64] fp32 directly.
__global__ __launch_bounds__(256)
void gemm0_k(const float* __restrict__ x, const u16* __restrict__ Wt,
             const float* __restrict__ dinv, u16* __restrict__ B, int N) {
  __shared__ u16 sw[128 * 136];
  const int t = threadIdx.x;
  stage_w(Wt, sw, t);
  __syncthreads();
  const int w = t >> 6;
  const int lane = t & 63;
  const int m = lane & 15;
  const int qd = lane >> 4;
  const int arow = blockIdx.x * 64 + w * 16 + m;
  short8 afr[4];
  if (arow < N) {
    const float* xp = x + (size_t)arow * 64;
    float v0[8], v1[8];
    *(float4*)&v0[0] = *(const float4*)(xp + 8 * qd);
    *(float4*)&v0[4] = *(const float4*)(xp + 8 * qd + 4);
    *(float4*)&v1[0] = *(const float4*)(xp + 32 + 8 * qd);
    *(float4*)&v1[4] = *(const float4*)(xp + 32 + 8 * qd + 4);
#pragma unroll
    for (int j = 0; j < 8; ++j) {
      bool n0 = isnan(v0[j]), n1 = isnan(v1[j]);
      afr[0][j] = (short)f2bf(n0 ? 0.f : v0[j]);
      afr[1][j] = (short)f2bf(n1 ? 0.f : v1[j]);
      afr[2][j] = (short)(n0 ? 0x3F80 : 0);
      afr[3][j] = (short)(n1 ? 0x3F80 : 0);
    }
  } else {
    short8 z = {0, 0, 0, 0, 0, 0, 0, 0};
#pragma unroll
    for (int s = 0; s < 4; ++s) afr[s] = z;
  }
  gemm_core(sw, afr, m, qd, arow, dinv, B, N);
}

// generic GEMM: B = dinv-scaled rows of (A @ W), A bf16
__global__ __launch_bounds__(256)
void gemm_k(const u16* __restrict__ A, const u16* __restrict__ Wt,
            const float* __restrict__ dinv, u16* __restrict__ B, int N) {
  __shared__ u16 sw[128 * 136];
  const int t = threadIdx.x;
  stage_w(Wt, sw, t);
  __syncthreads();
  const int w = t >> 6;
  const int lane = t & 63;
  const int m = lane & 15;
  const int qd = lane >> 4;
  const int arow = blockIdx.x * 64 + w * 16 + m;
  short8 afr[4];
  if (arow < N) {
    const short8* ap = (const short8*)(A + (size_t)arow * HD);
#pragma unroll
    for (int s = 0; s < 4; ++s) afr[s] = ap[4 * s + qd];
  } else {
    short8 z = {0, 0, 0, 0, 0, 0, 0, 0};
#pragma unroll
    for (int s = 0; s < 4; ++s) afr[s] = z;
  }
  gemm_core(sw, afr, m, qd, arow, dinv, B, N);
}

__device__ __forceinline__ int seg_lower_bound(const int* b32, int N, int b) {
  int lo = 0, hi = N;
  while (lo < hi) {
    int mid = (lo + hi) >> 1;
    if (b32[mid] < b) lo = mid + 1; else hi = mid;
  }
  return lo;
}

// two-stage mean pool, stage 1 (bf16 input); atomic-free partials.
__global__ __launch_bounds__(128)
void pool1_k(const u16* __restrict__ A, const int* __restrict__ b32,
             float* __restrict__ part, int N) {
  __shared__ int sb[2];
  int b = blockIdx.y;
  if (threadIdx.x < 2) sb[threadIdx.x] = seg_lower_bound(b32, N, b + threadIdx.x);
  __syncthreads();
  int s = sb[0], e = sb[1];
  int j = threadIdx.x;
  float a0 = 0.f, a1 = 0.f, a2 = 0.f, a3 = 0.f;
  int len = e - s;
  if (len > 0) {
    int nch = gridDim.x;
    int ch = (len + nch - 1) / nch;
    int lo = s + blockIdx.x * ch;
    int hi = lo + ch; if (hi > e) hi = e;
    int n = lo;
    for (; n + 3 < hi; n += 4) {
      a0 += bf2f(A[(size_t)(n + 0) * HD + j]);
      a1 += bf2f(A[(size_t)(n + 1) * HD + j]);
      a2 += bf2f(A[(size_t)(n + 2) * HD + j]);
      a3 += bf2f(A[(size_t)(n + 3) * HD + j]);
    }
    for (; n < hi; ++n) a0 += bf2f(A[(size_t)n * HD + j]);
  }
  part[((size_t)b * PCH + blockIdx.x) * HD + j] = (a0 + a1) + (a2 + a3);
}

// out = gelu((mean)@mW1+mb1) @ mW2 + mb2 ; mean from PCH partials
__global__ __launch_bounds__(128)
void mlp_k(const float* __restrict__ part, const int* __restrict__ b32,
           const float* __restrict__ mW1, const float* __restrict__ mb1,
           const float* __restrict__ mW2, const float* __restrict__ mb2,
           float* __restrict__ out, int N) {
  __shared__ float sg[128];
  __shared__ float st[128];
  __shared__ int sb[2];
  int b = blockIdx.x, j = threadIdx.x;
  if (j < 2) sb[j] = seg_lower_bound(b32, N, b + j);
  __syncthreads();
  int cnt = sb[1] - sb[0];
  float inv = 1.0f / (float)(cnt > 0 ? cnt : 1);
  float s0 = 0.f;
#pragma unroll
  for (int c = 0; c < PCH; ++c) s0 += part[((size_t)b * PCH + c) * HD + j];
  sg[j] = s0 * inv;
  __syncthreads();
  float s = mb1[j];
#pragma unroll 4
  for (int i = 0; i < 128; ++i) s += sg[i] * mW1[i * 128 + j];
  float ge = 0.5f * s * (1.0f + erff(s * 0.70710678118654752f));
  st[j] = ge;
  __syncthreads();
  if (j < OUTD) {
    float o = mb2[j];
#pragma unroll 4
    for (int k = 0; k < 128; ++k) o += st[k] * mW2[k * OUTD + j];
    out[b * OUTD + j] = o;
  }
}

// ---------------------------------------------------------------- launch
extern "C" void kernel_launch(void* const* d_in, const int* in_sizes, int n_in,
                              void* d_out, int out_size, void* d_ws, size_t ws_size,
                              hipStream_t stream) {
  const float* x   = (const float*)d_in[0];
  const int* ei    = (const int*)d_in[1];
  const float* ea  = (const float*)d_in[2];
  const int* bt    = (const int*)d_in[3];
  const float* W0  = (const float*)d_in[4];
  const float* b0  = (const float*)d_in[5];
  const float* W1  = (const float*)d_in[6];
  const float* b1  = (const float*)d_in[7];
  const float* W2  = (const float*)d_in[8];
  const float* b2  = (const float*)d_in[9];
  const float* bng = (const float*)d_in[10];
  const float* bnb = (const float*)d_in[11];
  const float* bnm = (const float*)d_in[12];
  const float* bnv = (const float*)d_in[13];
  const float* mW1 = (const float*)d_in[14];
  const float* mb1 = (const float*)d_in[15];
  const float* mW2 = (const float*)d_in[16];
  const float* mb2 = (const float*)d_in[17];
  float* out = (float*)d_out;

  const int N = in_sizes[0] / 64;      // 50000  (rows fit in 16 bits)
  const int E = in_sizes[2];           // 800000

  char* ws = (char*)d_ws;
  size_t NB2 = (size_t)N * HD * 2;     // bf16 feature buffer
  u16* A       = (u16*)(ws);
  u16* B       = (u16*)(ws + NB2);
  char* q      = ws + 2 * NB2;
  float* part  = (float*)q;            q += (size_t)GD * PCH * HD * 4;
  u16* Wt      = (u16*)q;              q += (size_t)3 * HD * HD * 2;
  int2* csc    = (int2*)q;             q += (size_t)E * 8;
  int2* tmp    = (int2*)q;             q += (size_t)E * 8;
  int gE  = (E + 255) / 256;
  int*   Hist  = (int*)q;              q += (size_t)gE * 256 * 4;
  int*   Off   = (int*)q;              q += (size_t)gE * 256 * 4;
  int*   totals= (int*)q;              q += 256 * 4;
  float* dinv  = (float*)q;            q += (size_t)N * 4;
  int*   offs  = (int*)q;              q += (size_t)(N + 2) * 4;
  int*   b32   = (int*)q;              q += (size_t)N * 4;

  dim3 blk(256);
  int gN   = (N + 255) / 256;
  int nbuk = gN;                       // col buckets (col>>8)

  hist_k<<<gE, blk, 0, stream>>>(ei, bt, b32, Hist, W0, W1, W2, Wt, offs, E, N);
  scan_k<<<nbuk, blk, 0, stream>>>(Hist, Off, totals, gE);
  scat_k<<<gE, blk, 0, stream>>>(ei, ea, totals, Off, tmp, E, N, nbuk);
  sort_k<<<nbuk, blk, 0, stream>>>(tmp, totals, csc, offs, dinv, N, nbuk);

  int gGemm = (N + 63) / 64;
  int nbh  = (N + 31) / 32;
  int nb4  = (nbh + 3) / 4;
  int gAgg = nb4 * 8;

  // layer 0 GEMM: C0 = dinv*(h0@W0)   (h0 built in the A-fragment load)
  gemm0_k<<<gGemm, 256, 0, stream>>>(x, Wt, dinv, B, N);
  aggregate_k<<<gAgg, blk, 0, stream>>>(offs, csc, B, dinv, b0,
                                        bng, bnb, bnm, bnv, 1, A, N, nbh);
  // layer 1
  gemm_k<<<gGemm, 256, 0, stream>>>(A, Wt + HD * HD, dinv, B, N);
  aggregate_k<<<gAgg, blk, 0, stream>>>(offs, csc, B, dinv, b1,
                                        bng, bnb, bnm, bnv, 1, A, N, nbh);
  // layer 2 (no bn/relu)
  gemm_k<<<gGemm, 256, 0, stream>>>(A, Wt + 2 * HD * HD, dinv, B, N);
  aggregate_k<<<gAgg, blk, 0, stream>>>(offs, csc, B, dinv, b2,
                                        bng, bnb, bnm, bnv, 0, A, N, nbh);

  dim3 pgrid(PCH, GD);
  pool1_k<<<pgrid, 128, 0, stream>>>(A, b32, part, N);
  mlp_k<<<GD, 128, 0, stream>>>(part, b32, mW1, mb1, mW2, mb2, out, N);
}

// Round 12
// 299.794 us; speedup vs baseline: 1.1850x; 1.0282x over previous
//
#include <hip/hip_runtime.h>
#include <hip/hip_bf16.h>
#include <stdint.h>

#define HD 128
#define GD 64
#define OUTD 16
#define PCH 32  // pool chunks per graph

typedef unsigned short u16;
typedef unsigned int u32;
typedef unsigned char u8;
typedef __attribute__((ext_vector_type(8))) short short8;
typedef __attribute__((ext_vector_type(2))) float f32x2;
typedef __attribute__((ext_vector_type(4))) float f32x4;
typedef __attribute__((ext_vector_type(4))) unsigned short u16x4;

__device__ __forceinline__ float bf2f(u16 u) {
  union { uint32_t i; float f; } v; v.i = ((uint32_t)u) << 16; return v.f;
}
__device__ __forceinline__ u16 f2bf(float f) {
  union { __hip_bfloat16 h; u16 u; } v; v.h = __float2bfloat16(f); return v.u;
}

// exclusive scan of 256 per-thread values via LDS (Hillis-Steele).
__device__ __forceinline__ u32 excl_scan256(u32 v, u32* s, int t, u32* total) {
  s[t] = v;
  __syncthreads();
#pragma unroll
  for (int off = 1; off < 256; off <<= 1) {
    u32 x = (t >= off) ? s[t - off] : 0u;
    __syncthreads();
    s[t] += x;
    __syncthreads();
  }
  u32 incl = s[t];
  u32 tot = s[255];
  __syncthreads();
  *total = tot;
  return incl - v;
}

__device__ __forceinline__ int detect_is64(const int* ei) {
  int all0 = 1;
  for (int k = 1; k < 128; k += 2) all0 &= (ei[k] == 0);
  return all0;
}

// K1: per-block LDS histogram over col-buckets (col>>8); no global atomics.
// Fused: batch convert, W transpose/convert (first 192 blocks), offs[N]=E.
__global__ __launch_bounds__(256)
void hist_k(const int* __restrict__ ei, const int* __restrict__ bt,
            int* __restrict__ b32, int* __restrict__ Hist,
            const float* __restrict__ W0, const float* __restrict__ W1,
            const float* __restrict__ W2, u16* __restrict__ Wt,
            int* __restrict__ offs, int E, int N) {
  __shared__ int h[256];
  __shared__ int s_is64;
  h[threadIdx.x] = 0;
  if (threadIdx.x == 0) s_is64 = detect_is64(ei);
  __syncthreads();
  int is64 = s_is64;
  int i = blockIdx.x * 256 + threadIdx.x;
  if (i == 0) offs[N] = E;
  if (i < E) {
    int c = is64 ? ei[2 * (E + i)] : ei[E + i];
    c = (c < 0) ? 0 : (c >= N ? N - 1 : c);
    atomicAdd(&h[c >> 8], 1);              // LDS atomic
  }
  if (i < N) {
    int v = is64 ? bt[2 * i] : bt[i];
    b32[i] = (v < 0) ? 0 : (v >= GD ? GD - 1 : v);
  }
  if (i < 3 * HD * HD) {
    int l = i / (HD * HD);
    int r = i - l * (HD * HD);
    int n = r >> 7, k = r & 127;
    const float* W = (l == 0) ? W0 : (l == 1) ? W1 : W2;
    Wt[i] = f2bf(W[k * HD + n]);
  }
  __syncthreads();
  Hist[(size_t)blockIdx.x * 256 + threadIdx.x] = h[threadIdx.x];
}

// K2: for bucket b = blockIdx, exclusive-scan Hist[*][b] across blocks.
__global__ __launch_bounds__(256)
void scan_k(const int* __restrict__ Hist, int* __restrict__ Off,
            int* __restrict__ totals, int nblk) {
  __shared__ u32 s[256];
  int b = blockIdx.x, t = threadIdx.x;
  int chunk = (nblk + 255) >> 8;
  int i0 = t * chunk;
  int i1 = i0 + chunk; if (i1 > nblk) i1 = nblk;
  u32 part = 0;
  for (int i = i0; i < i1; ++i) part += (u32)Hist[(size_t)i * 256 + b];
  u32 tot;
  u32 run = excl_scan256(part, s, t, &tot);
  for (int i = i0; i < i1; ++i) {
    u32 h = (u32)Hist[(size_t)i * 256 + b];
    Off[(size_t)i * 256 + b] = (int)run;
    run += h;
  }
  if (t == 0) totals[b] = (int)tot;
}

// K3: scatter edges into bucket-partitioned tmp; LDS cursors only.
// Bucket bases computed inline from totals (in-LDS scan).
__global__ __launch_bounds__(256)
void scat_k(const int* __restrict__ ei, const float* __restrict__ ea,
            const int* __restrict__ totals, const int* __restrict__ Off,
            int2* __restrict__ tmp, int E, int N, int nbuk) {
  __shared__ u32 s[256];
  __shared__ u32 cur[256];
  __shared__ int s_is64;
  int t = threadIdx.x;
  if (t == 0) s_is64 = detect_is64(ei);
  u32 v = (t < nbuk) ? (u32)totals[t] : 0u;
  u32 tot;
  u32 base = excl_scan256(v, s, t, &tot);
  cur[t] = (t < nbuk)
         ? (base + (u32)Off[(size_t)blockIdx.x * 256 + t]) : 0u;
  __syncthreads();
  int is64 = s_is64;
  int i = blockIdx.x * 256 + t;
  if (i >= E) return;
  int r = is64 ? ei[2 * i] : ei[i];
  int c = is64 ? ei[2 * (E + i)] : ei[E + i];
  r = (r < 0) ? 0 : (r >= N ? N - 1 : r);
  c = (c < 0) ? 0 : (c >= N ? N - 1 : c);
  float a = ea[i];
  float w = isnan(a) ? 0.f : fabsf(a);
  u32 pos = atomicAdd(&cur[c >> 8], 1u);  // LDS atomic
  tmp[pos] = make_int2((int)(((u32)(c & 255) << 16) | (u32)r), __float_as_int(w));
}

// K4: per-bucket column sort into final csc + offs; bucket base inline.
// Fused: dinv[col] = rsqrt(colsum(|w|)+1) via re-read of the block's
// just-written (L2-hot) csc range.
__global__ __launch_bounds__(256)
void sort_k(const int2* __restrict__ tmp, const int* __restrict__ totals,
            int2* __restrict__ csc, int* __restrict__ offs,
            float* __restrict__ dinv, int N, int nbuk) {
  __shared__ u32 cnt[256];
  __shared__ u32 s[256];
  __shared__ u32 cur[256];
  __shared__ u32 bb[256];
  int b = blockIdx.x, t = threadIdx.x;
  u32 v = (t < nbuk) ? (u32)totals[t] : 0u;
  u32 tot;
  u32 base = excl_scan256(v, s, t, &tot);
  bb[t] = base;
  cnt[t] = 0;
  __syncthreads();
  int s0 = (int)bb[b];
  int s1 = s0 + totals[b];
  for (int p = s0 + t; p < s1; p += 256) {
    u32 rc = (u32)tmp[p].x;
    atomicAdd(&cnt[rc >> 16], 1u);
  }
  __syncthreads();
  u32 myc = cnt[t];
  u32 excl = excl_scan256(myc, s, t, &tot);
  u32 st = (u32)s0 + excl;
  int col = (b << 8) + t;
  if (col < N) offs[col] = (int)st;
  cur[t] = st;
  __syncthreads();
  for (int p = s0 + t; p < s1; p += 256) {
    int2 r = tmp[p];
    u32 rc = (u32)r.x;
    u32 pos = atomicAdd(&cur[rc >> 16], 1u);
    csc[pos] = make_int2((int)(rc & 0xFFFFu), r.y);
  }
  __syncthreads();
  if (col < N) {
    float ssum = 0.f;
    for (u32 p = st; p < st + myc; ++p) ssum += __int_as_float(csc[p].y);
    dinv[col] = rsqrtf(ssum + 1.0f);
  }
}

// fp8 decode helper (gfx950 OCP e4m3; encode/decode via same HW instrs so
// the roundtrip is self-consistent).  v_cvt_pk_f32_fp8 decodes 2 fp8/instr;
// word-half selector must be a literal constant.
__device__ __forceinline__ void fma_fp8x4(float* acc, float w, int h) {
  f32x2 lo = __builtin_amdgcn_cvt_pk_f32_fp8(h, false);
  f32x2 hi = __builtin_amdgcn_cvt_pk_f32_fp8(h, true);
  acc[0] += w * lo[0];
  acc[1] += w * lo[1];
  acc[2] += w * hi[0];
  acc[3] += w * hi[1];
}
__device__ __forceinline__ void fma_fp8x16(float* acc, float w, int4 h) {
  fma_fp8x4(acc,      w, h.x);
  fma_fp8x4(acc + 4,  w, h.y);
  fma_fp8x4(acc + 8,  w, h.z);
  fma_fp8x4(acc + 12, w, h.w);
}

// Fused: A[n] = BN?ReLU( dinv[n]*(C[n] + sum_in w*C[row]) + bias )
// UNSPLIT, fp8-gather: 8 lanes/node x 16 feats; each edge gather is ONE
// 16B fp8 load per lane (128B/edge total = one line, working set 6.4MB —
// the half-split working set at unsplit pass count).  Self term from
// exact bf16 B.  No LDS -> max occupancy (r8 lesson).
__global__ __launch_bounds__(256)
void aggregate_k(const int* __restrict__ offs, const int2* __restrict__ csc,
                 const u16* __restrict__ B, const u8* __restrict__ B8,
                 const float* __restrict__ dinv,
                 const float* __restrict__ bias, const float* __restrict__ gamma,
                 const float* __restrict__ beta, const float* __restrict__ mean,
                 const float* __restrict__ var, int do_bn,
                 u16* __restrict__ A, int N) {
  int tid = blockIdx.x * 256 + threadIdx.x;
  int n = tid >> 3;
  if (n >= N) return;
  int f0 = (tid & 7) << 4;   // 16 features per lane
  float acc[16];
  short8 b0 = *(const short8*)(B + (size_t)n * HD + f0);
  short8 b1 = *(const short8*)(B + (size_t)n * HD + f0 + 8);
#pragma unroll
  for (int j = 0; j < 8; ++j) { acc[j] = bf2f((u16)b0[j]); acc[8 + j] = bf2f((u16)b1[j]); }

  int p = offs[n], pe = offs[n + 1];
  for (; p + 7 < pe; p += 8) {
    int2 e[8];
    int4 h[8];
#pragma unroll
    for (int u = 0; u < 8; ++u) e[u] = csc[p + u];
#pragma unroll
    for (int u = 0; u < 8; ++u) h[u] = *(const int4*)(B8 + (size_t)e[u].x * HD + f0);
#pragma unroll
    for (int u = 0; u < 8; ++u) fma_fp8x16(acc, __int_as_float(e[u].y), h[u]);
  }
  for (; p + 1 < pe; p += 2) {
    int2 e0 = csc[p], e1 = csc[p + 1];
    int4 h0 = *(const int4*)(B8 + (size_t)e0.x * HD + f0);
    int4 h1 = *(const int4*)(B8 + (size_t)e1.x * HD + f0);
    fma_fp8x16(acc, __int_as_float(e0.y), h0);
    fma_fp8x16(acc, __int_as_float(e1.y), h1);
  }
  if (p < pe) {
    int2 e0 = csc[p];
    int4 h0 = *(const int4*)(B8 + (size_t)e0.x * HD + f0);
    fma_fp8x16(acc, __int_as_float(e0.y), h0);
  }

  float dn = dinv[n];
#pragma unroll
  for (int q = 0; q < 16; ++q) acc[q] = dn * acc[q] + bias[f0 + q];
  if (do_bn) {
#pragma unroll
    for (int q = 0; q < 16; ++q) {
      float s = gamma[f0 + q] * rsqrtf(var[f0 + q] + 1e-5f);
      float v = (acc[q] - mean[f0 + q]) * s + beta[f0 + q];
      acc[q] = v > 0.f ? v : 0.f;
    }
  }
  short8 o0, o1;
#pragma unroll
  for (int q = 0; q < 8; ++q) { o0[q] = (short)f2bf(acc[q]); o1[q] = (short)f2bf(acc[8 + q]); }
  *(short8*)(A + (size_t)n * HD + f0) = o0;
  *(short8*)(A + (size_t)n * HD + f0 + 8) = o1;
}

// ---- shared MFMA core (operands swapped: mfma(W_frag, A_frag)).
// Epilogue: bf16 B + fp8 shadow B8 (gather copy), one dinv scalar.
__device__ __forceinline__ void gemm_core(const u16* sw, const short8* afr,
                                          int m, int qd, int arow,
                                          const float* __restrict__ dinv,
                                          u16* __restrict__ B, u8* __restrict__ B8,
                                          int N) {
  const bool ok = (arow < N);
  const float dr = ok ? dinv[arow] : 0.f;
#pragma unroll
  for (int c = 0; c < 8; ++c) {
    f32x4 acc = {0.f, 0.f, 0.f, 0.f};
    const int n = c * 16 + m;
#pragma unroll
    for (int s = 0; s < 4; ++s) {
      short8 bfr = *(const short8*)(sw + n * 136 + 32 * s + 8 * qd);
      acc = __builtin_amdgcn_mfma_f32_16x16x32_bf16(bfr, afr[s], acc, 0, 0, 0);
    }
    if (ok) {
      float v0 = dr * acc[0], v1 = dr * acc[1], v2 = dr * acc[2], v3 = dr * acc[3];
      u16x4 o;
      o[0] = f2bf(v0); o[1] = f2bf(v1); o[2] = f2bf(v2); o[3] = f2bf(v3);
      *(u16x4*)(B + (size_t)arow * HD + c * 16 + qd * 4) = o;
      int w8 = 0;
      w8 = __builtin_amdgcn_cvt_pk_fp8_f32(v0, v1, w8, false);
      w8 = __builtin_amdgcn_cvt_pk_fp8_f32(v2, v3, w8, true);
      *(int*)(B8 + (size_t)arow * HD + c * 16 + qd * 4) = w8;
    }
  }
}

__device__ __forceinline__ void stage_w(const u16* __restrict__ Wt, u16* sw, int t) {
  const uint32_t* src = (const uint32_t*)Wt;
  uint32_t* dst = (uint32_t*)sw;
#pragma unroll
  for (int k = 0; k < 32; ++k) {
    int q = t + k * 256;
    int r = q >> 6;
    int u = q & 63;
    dst[r * 68 + u] = src[r * 64 + u];
  }
}

// layer-0 GEMM with fused h0 construction: reads x[N,64] fp32 directly.
__global__ __launch_bounds__(256)
void gemm0_k(const float* __restrict__ x, const u16* __restrict__ Wt,
             const float* __restrict__ dinv, u16* __restrict__ B,
             u8* __restrict__ B8, int N) {
  __shared__ u16 sw[128 * 136];
  const int t = threadIdx.x;
  stage_w(Wt, sw, t);
  __syncthreads();
  const int w = t >> 6;
  const int lane = t & 63;
  const int m = lane & 15;
  const int qd = lane >> 4;
  const int arow = blockIdx.x * 64 + w * 16 + m;
  short8 afr[4];
  if (arow < N) {
    const float* xp = x + (size_t)arow * 64;
    float v0[8], v1[8];
    *(float4*)&v0[0] = *(const float4*)(xp + 8 * qd);
    *(float4*)&v0[4] = *(const float4*)(xp + 8 * qd + 4);
    *(float4*)&v1[0] = *(const float4*)(xp + 32 + 8 * qd);
    *(float4*)&v1[4] = *(const float4*)(xp + 32 + 8 * qd + 4);
#pragma unroll
    for (int j = 0; j < 8; ++j) {
      bool n0 = isnan(v0[j]), n1 = isnan(v1[j]);
      afr[0][j] = (short)f2bf(n0 ? 0.f : v0[j]);
      afr[1][j] = (short)f2bf(n1 ? 0.f : v1[j]);
      afr[2][j] = (short)(n0 ? 0x3F80 : 0);
      afr[3][j] = (short)(n1 ? 0x3F80 : 0);
    }
  } else {
    short8 z = {0, 0, 0, 0, 0, 0, 0, 0};
#pragma unroll
    for (int s = 0; s < 4; ++s) afr[s] = z;
  }
  gemm_core(sw, afr, m, qd, arow, dinv, B, B8, N);
}

// generic GEMM: B = dinv-scaled rows of (A @ W), A bf16
__global__ __launch_bounds__(256)
void gemm_k(const u16* __restrict__ A, const u16* __restrict__ Wt,
            const float* __restrict__ dinv, u16* __restrict__ B,
            u8* __restrict__ B8, int N) {
  __shared__ u16 sw[128 * 136];
  const int t = threadIdx.x;
  stage_w(Wt, sw, t);
  __syncthreads();
  const int w = t >> 6;
  const int lane = t & 63;
  const int m = lane & 15;
  const int qd = lane >> 4;
  const int arow = blockIdx.x * 64 + w * 16 + m;
  short8 afr[4];
  if (arow < N) {
    const short8* ap = (const short8*)(A + (size_t)arow * HD);
#pragma unroll
    for (int s = 0; s < 4; ++s) afr[s] = ap[4 * s + qd];
  } else {
    short8 z = {0, 0, 0, 0, 0, 0, 0, 0};
#pragma unroll
    for (int s = 0; s < 4; ++s) afr[s] = z;
  }
  gemm_core(sw, afr, m, qd, arow, dinv, B, B8, N);
}

__device__ __forceinline__ int seg_lower_bound(const int* b32, int N, int b) {
  int lo = 0, hi = N;
  while (lo < hi) {
    int mid = (lo + hi) >> 1;
    if (b32[mid] < b) lo = mid + 1; else hi = mid;
  }
  return lo;
}

// two-stage mean pool, stage 1 (bf16 input); atomic-free partials.
__global__ __launch_bounds__(128)
void pool1_k(const u16* __restrict__ A, const int* __restrict__ b32,
             float* __restrict__ part, int N) {
  __shared__ int sb[2];
  int b = blockIdx.y;
  if (threadIdx.x < 2) sb[threadIdx.x] = seg_lower_bound(b32, N, b + threadIdx.x);
  __syncthreads();
  int s = sb[0], e = sb[1];
  int j = threadIdx.x;
  float a0 = 0.f, a1 = 0.f, a2 = 0.f, a3 = 0.f;
  int len = e - s;
  if (len > 0) {
    int nch = gridDim.x;
    int ch = (len + nch - 1) / nch;
    int lo = s + blockIdx.x * ch;
    int hi = lo + ch; if (hi > e) hi = e;
    int n = lo;
    for (; n + 3 < hi; n += 4) {
      a0 += bf2f(A[(size_t)(n + 0) * HD + j]);
      a1 += bf2f(A[(size_t)(n + 1) * HD + j]);
      a2 += bf2f(A[(size_t)(n + 2) * HD + j]);
      a3 += bf2f(A[(size_t)(n + 3) * HD + j]);
    }
    for (; n < hi; ++n) a0 += bf2f(A[(size_t)n * HD + j]);
  }
  part[((size_t)b * PCH + blockIdx.x) * HD + j] = (a0 + a1) + (a2 + a3);
}

// out = gelu((mean)@mW1+mb1) @ mW2 + mb2 ; mean from PCH partials
__global__ __launch_bounds__(128)
void mlp_k(const float* __restrict__ part, const int* __restrict__ b32,
           const float* __restrict__ mW1, const float* __restrict__ mb1,
           const float* __restrict__ mW2, const float* __restrict__ mb2,
           float* __restrict__ out, int N) {
  __shared__ float sg[128];
  __shared__ float st[128];
  __shared__ int sb[2];
  int b = blockIdx.x, j = threadIdx.x;
  if (j < 2) sb[j] = seg_lower_bound(b32, N, b + j);
  __syncthreads();
  int cnt = sb[1] - sb[0];
  float inv = 1.0f / (float)(cnt > 0 ? cnt : 1);
  float s0 = 0.f;
#pragma unroll
  for (int c = 0; c < PCH; ++c) s0 += part[((size_t)b * PCH + c) * HD + j];
  sg[j] = s0 * inv;
  __syncthreads();
  float s = mb1[j];
#pragma unroll 4
  for (int i = 0; i < 128; ++i) s += sg[i] * mW1[i * 128 + j];
  float ge = 0.5f * s * (1.0f + erff(s * 0.70710678118654752f));
  st[j] = ge;
  __syncthreads();
  if (j < OUTD) {
    float o = mb2[j];
#pragma unroll 4
    for (int k = 0; k < 128; ++k) o += st[k] * mW2[k * OUTD + j];
    out[b * OUTD + j] = o;
  }
}

// ---------------------------------------------------------------- launch
extern "C" void kernel_launch(void* const* d_in, const int* in_sizes, int n_in,
                              void* d_out, int out_size, void* d_ws, size_t ws_size,
                              hipStream_t stream) {
  const float* x   = (const float*)d_in[0];
  const int* ei    = (const int*)d_in[1];
  const float* ea  = (const float*)d_in[2];
  const int* bt    = (const int*)d_in[3];
  const float* W0  = (const float*)d_in[4];
  const float* b0  = (const float*)d_in[5];
  const float* W1  = (const float*)d_in[6];
  const float* b1  = (const float*)d_in[7];
  const float* W2  = (const float*)d_in[8];
  const float* b2  = (const float*)d_in[9];
  const float* bng = (const float*)d_in[10];
  const float* bnb = (const float*)d_in[11];
  const float* bnm = (const float*)d_in[12];
  const float* bnv = (const float*)d_in[13];
  const float* mW1 = (const float*)d_in[14];
  const float* mb1 = (const float*)d_in[15];
  const float* mW2 = (const float*)d_in[16];
  const float* mb2 = (const float*)d_in[17];
  float* out = (float*)d_out;

  const int N = in_sizes[0] / 64;      // 50000  (rows fit in 16 bits)
  const int E = in_sizes[2];           // 800000

  char* ws = (char*)d_ws;
  size_t NB2 = (size_t)N * HD * 2;     // bf16 feature buffer
  u16* A       = (u16*)(ws);
  u16* B       = (u16*)(ws + NB2);
  char* q      = ws + 2 * NB2;
  u8*  B8      = (u8*)q;               q += (size_t)N * HD;   // fp8 shadow
  float* part  = (float*)q;            q += (size_t)GD * PCH * HD * 4;
  u16* Wt      = (u16*)q;              q += (size_t)3 * HD * HD * 2;
  int2* csc    = (int2*)q;             q += (size_t)E * 8;
  int2* tmp    = (int2*)q;             q += (size_t)E * 8;
  int gE  = (E + 255) / 256;
  int*   Hist  = (int*)q;              q += (size_t)gE * 256 * 4;
  int*   Off   = (int*)q;              q += (size_t)gE * 256 * 4;
  int*   totals= (int*)q;              q += 256 * 4;
  float* dinv  = (float*)q;            q += (size_t)N * 4;
  int*   offs  = (int*)q;              q += (size_t)(N + 2) * 4;
  int*   b32   = (int*)q;              q += (size_t)N * 4;

  dim3 blk(256);
  int gN   = (N + 255) / 256;
  int nbuk = gN;                       // col buckets (col>>8)

  hist_k<<<gE, blk, 0, stream>>>(ei, bt, b32, Hist, W0, W1, W2, Wt, offs, E, N);
  scan_k<<<nbuk, blk, 0, stream>>>(Hist, Off, totals, gE);
  scat_k<<<gE, blk, 0, stream>>>(ei, ea, totals, Off, tmp, E, N, nbuk);
  sort_k<<<nbuk, blk, 0, stream>>>(tmp, totals, csc, offs, dinv, N, nbuk);

  int gGemm = (N + 63) / 64;
  int gAgg  = (N * 8 + 255) / 256;

  // layer 0 GEMM: C0 = dinv*(h0@W0)   (h0 built in the A-fragment load)
  gemm0_k<<<gGemm, 256, 0, stream>>>(x, Wt, dinv, B, B8, N);
  aggregate_k<<<gAgg, blk, 0, stream>>>(offs, csc, B, B8, dinv, b0,
                                        bng, bnb, bnm, bnv, 1, A, N);
  // layer 1
  gemm_k<<<gGemm, 256, 0, stream>>>(A, Wt + HD * HD, dinv, B, B8, N);
  aggregate_k<<<gAgg, blk, 0, stream>>>(offs, csc, B, B8, dinv, b1,
                                        bng, bnb, bnm, bnv, 1, A, N);
  // layer 2 (no bn/relu)
  gemm_k<<<gGemm, 256, 0, stream>>>(A, Wt + 2 * HD * HD, dinv, B, B8, N);
  aggregate_k<<<gAgg, blk, 0, stream>>>(offs, csc, B, B8, dinv, b2,
                                        bng, bnb, bnm, bnv, 0, A, N);

  dim3 pgrid(PCH, GD);
  pool1_k<<<pgrid, 128, 0, stream>>>(A, b32, part, N);
  mlp_k<<<GD, 128, 0, stream>>>(part, b32, mW1, mb1, mW2, mb2, out, N);
}

// Round 13
// 299.314 us; speedup vs baseline: 1.1869x; 1.0016x over previous
//
#include <hip/hip_runtime.h>
#include <hip/hip_bf16.h>
#include <stdint.h>

#define HD 128
#define GD 64
#define OUTD 16
#define PCH 32  // pool chunks per graph

typedef unsigned short u16;
typedef unsigned int u32;
typedef unsigned char u8;
typedef unsigned long long u64;
typedef __attribute__((ext_vector_type(8))) short short8;
typedef __attribute__((ext_vector_type(2))) float f32x2;
typedef __attribute__((ext_vector_type(4))) float f32x4;
typedef __attribute__((ext_vector_type(4))) unsigned short u16x4;

__device__ __forceinline__ float bf2f(u16 u) {
  union { uint32_t i; float f; } v; v.i = ((uint32_t)u) << 16; return v.f;
}
__device__ __forceinline__ u16 f2bf(float f) {
  union { __hip_bfloat16 h; u16 u; } v; v.h = __float2bfloat16(f); return v.u;
}

// exclusive scan of 256 per-thread values via LDS (Hillis-Steele).
__device__ __forceinline__ u32 excl_scan256(u32 v, u32* s, int t, u32* total) {
  s[t] = v;
  __syncthreads();
#pragma unroll
  for (int off = 1; off < 256; off <<= 1) {
    u32 x = (t >= off) ? s[t - off] : 0u;
    __syncthreads();
    s[t] += x;
    __syncthreads();
  }
  u32 incl = s[t];
  u32 tot = s[255];
  __syncthreads();
  *total = tot;
  return incl - v;
}

__device__ __forceinline__ int detect_is64(const int* ei) {
  int all0 = 1;
  for (int k = 1; k < 128; k += 2) all0 &= (ei[k] == 0);
  return all0;
}

// K1: per-block LDS histogram over col-buckets (col>>8); no global atomics.
// Fused: batch convert, W transpose/convert (first 192 blocks), offs[N]=E.
__global__ __launch_bounds__(256)
void hist_k(const int* __restrict__ ei, const int* __restrict__ bt,
            int* __restrict__ b32, int* __restrict__ Hist,
            const float* __restrict__ W0, const float* __restrict__ W1,
            const float* __restrict__ W2, u16* __restrict__ Wt,
            int* __restrict__ offs, int E, int N) {
  __shared__ int h[256];
  __shared__ int s_is64;
  h[threadIdx.x] = 0;
  if (threadIdx.x == 0) s_is64 = detect_is64(ei);
  __syncthreads();
  int is64 = s_is64;
  int i = blockIdx.x * 256 + threadIdx.x;
  if (i == 0) offs[N] = E;
  if (i < E) {
    int c = is64 ? ei[2 * (E + i)] : ei[E + i];
    c = (c < 0) ? 0 : (c >= N ? N - 1 : c);
    atomicAdd(&h[c >> 8], 1);              // LDS atomic
  }
  if (i < N) {
    int v = is64 ? bt[2 * i] : bt[i];
    b32[i] = (v < 0) ? 0 : (v >= GD ? GD - 1 : v);
  }
  if (i < 3 * HD * HD) {
    int l = i / (HD * HD);
    int r = i - l * (HD * HD);
    int n = r >> 7, k = r & 127;
    const float* W = (l == 0) ? W0 : (l == 1) ? W1 : W2;
    Wt[i] = f2bf(W[k * HD + n]);
  }
  __syncthreads();
  Hist[(size_t)blockIdx.x * 256 + threadIdx.x] = h[threadIdx.x];
}

// K2: for bucket b = blockIdx, exclusive-scan Hist[*][b] across blocks.
__global__ __launch_bounds__(256)
void scan_k(const int* __restrict__ Hist, int* __restrict__ Off,
            int* __restrict__ totals, int nblk) {
  __shared__ u32 s[256];
  int b = blockIdx.x, t = threadIdx.x;
  int chunk = (nblk + 255) >> 8;
  int i0 = t * chunk;
  int i1 = i0 + chunk; if (i1 > nblk) i1 = nblk;
  u32 part = 0;
  for (int i = i0; i < i1; ++i) part += (u32)Hist[(size_t)i * 256 + b];
  u32 tot;
  u32 run = excl_scan256(part, s, t, &tot);
  for (int i = i0; i < i1; ++i) {
    u32 h = (u32)Hist[(size_t)i * 256 + b];
    Off[(size_t)i * 256 + b] = (int)run;
    run += h;
  }
  if (t == 0) totals[b] = (int)tot;
}

// K3: scatter edges into bucket-partitioned tmp; LDS cursors only.
// Bucket bases computed inline from totals (in-LDS scan).
__global__ __launch_bounds__(256)
void scat_k(const int* __restrict__ ei, const float* __restrict__ ea,
            const int* __restrict__ totals, const int* __restrict__ Off,
            int2* __restrict__ tmp, int E, int N, int nbuk) {
  __shared__ u32 s[256];
  __shared__ u32 cur[256];
  __shared__ int s_is64;
  int t = threadIdx.x;
  if (t == 0) s_is64 = detect_is64(ei);
  u32 v = (t < nbuk) ? (u32)totals[t] : 0u;
  u32 tot;
  u32 base = excl_scan256(v, s, t, &tot);
  cur[t] = (t < nbuk)
         ? (base + (u32)Off[(size_t)blockIdx.x * 256 + t]) : 0u;
  __syncthreads();
  int is64 = s_is64;
  int i = blockIdx.x * 256 + t;
  if (i >= E) return;
  int r = is64 ? ei[2 * i] : ei[i];
  int c = is64 ? ei[2 * (E + i)] : ei[E + i];
  r = (r < 0) ? 0 : (r >= N ? N - 1 : r);
  c = (c < 0) ? 0 : (c >= N ? N - 1 : c);
  float a = ea[i];
  float w = isnan(a) ? 0.f : fabsf(a);
  u32 pos = atomicAdd(&cur[c >> 8], 1u);  // LDS atomic
  tmp[pos] = make_int2((int)(((u32)(c & 255) << 16) | (u32)r), __float_as_int(w));
}

// K4: per-bucket column sort into final csc + offs; bucket base inline.
// Fused: dinv[col] = rsqrt(colsum(|w|)+1) via re-read of the block's
// just-written (L2-hot) csc range.
__global__ __launch_bounds__(256)
void sort_k(const int2* __restrict__ tmp, const int* __restrict__ totals,
            int2* __restrict__ csc, int* __restrict__ offs,
            float* __restrict__ dinv, int N, int nbuk) {
  __shared__ u32 cnt[256];
  __shared__ u32 s[256];
  __shared__ u32 cur[256];
  __shared__ u32 bb[256];
  int b = blockIdx.x, t = threadIdx.x;
  u32 v = (t < nbuk) ? (u32)totals[t] : 0u;
  u32 tot;
  u32 base = excl_scan256(v, s, t, &tot);
  bb[t] = base;
  cnt[t] = 0;
  __syncthreads();
  int s0 = (int)bb[b];
  int s1 = s0 + totals[b];
  for (int p = s0 + t; p < s1; p += 256) {
    u32 rc = (u32)tmp[p].x;
    atomicAdd(&cnt[rc >> 16], 1u);
  }
  __syncthreads();
  u32 myc = cnt[t];
  u32 excl = excl_scan256(myc, s, t, &tot);
  u32 st = (u32)s0 + excl;
  int col = (b << 8) + t;
  if (col < N) offs[col] = (int)st;
  cur[t] = st;
  __syncthreads();
  for (int p = s0 + t; p < s1; p += 256) {
    int2 r = tmp[p];
    u32 rc = (u32)r.x;
    u32 pos = atomicAdd(&cur[rc >> 16], 1u);
    csc[pos] = make_int2((int)(rc & 0xFFFFu), r.y);
  }
  __syncthreads();
  if (col < N) {
    float ssum = 0.f;
    for (u32 p = st; p < st + myc; ++p) ssum += __int_as_float(csc[p].y);
    dinv[col] = rsqrtf(ssum + 1.0f);
  }
}

// fp8 decode (gfx950 OCP e4m3; same HW instrs as encode -> self-consistent
// roundtrip).  v_cvt_pk_f32_fp8 decodes 2 fp8/instr; literal half selector.
__device__ __forceinline__ void fma_fp8x8(float* acc, float w, int2 h) {
  f32x2 a0 = __builtin_amdgcn_cvt_pk_f32_fp8(h.x, false);
  f32x2 a1 = __builtin_amdgcn_cvt_pk_f32_fp8(h.x, true);
  f32x2 a2 = __builtin_amdgcn_cvt_pk_f32_fp8(h.y, false);
  f32x2 a3 = __builtin_amdgcn_cvt_pk_f32_fp8(h.y, true);
  acc[0] += w * a0[0]; acc[1] += w * a0[1];
  acc[2] += w * a1[0]; acc[3] += w * a1[1];
  acc[4] += w * a2[0]; acc[5] += w * a2[1];
  acc[6] += w * a3[0]; acc[7] += w * a3[1];
}

// non-temporal 8B load of a csc record (stream; don't pollute L2).
__device__ __forceinline__ int2 ld_nt8(const int2* p) {
  u64 v = __builtin_nontemporal_load((const u64*)p);
  int2 r; r.x = (int)(u32)(v & 0xFFFFFFFFull); r.y = (int)(u32)(v >> 32);
  return r;
}

// Fused: A[n] = BN?ReLU( dinv[n]*(C[n] + sum_in w*C[row]) + bias )
// HALF-SPLIT fp8-plane gather: pass half h gathers 8B/lane from plane
// B8[h] (N x 64B = 3.2MB contiguous < 4MB per-XCD L2 -> plane becomes
// L2-resident).  csc loads + A stores NON-TEMPORAL so the once-through
// stream can't evict the plane (r7 lesson: stream pollution killed
// residency).  XCD-slot mapping as r5/r10 winner.  No LDS (r8 lesson).
__global__ __launch_bounds__(256)
void aggregate_k(const int* __restrict__ offs, const int2* __restrict__ csc,
                 const u16* __restrict__ B, const u8* __restrict__ B8,
                 const float* __restrict__ dinv,
                 const float* __restrict__ bias, const float* __restrict__ gamma,
                 const float* __restrict__ beta, const float* __restrict__ mean,
                 const float* __restrict__ var, int do_bn,
                 u16* __restrict__ A, int N, int nbh) {
  int b = blockIdx.x;
  int half = (b >> 2) & 1;
  int j = (b & 3) | ((b >> 3) << 2);    // node-block index within half
  if (j >= nbh) return;
  int n = j * 32 + (threadIdx.x >> 3);
  if (n >= N) return;
  const int fl = (threadIdx.x & 7) << 3;   // feature offset within plane
  const int f8 = fl + (half << 6);         // global feature offset
  const u8* plane = B8 + (size_t)half * ((size_t)N * 64) + fl;
  float acc[8];
  short8 bu = *(const short8*)(B + (size_t)n * HD + f8);
#pragma unroll
  for (int u = 0; u < 8; ++u) acc[u] = bf2f((u16)bu[u]);   // self term C[n]

  int p = offs[n], pe = offs[n + 1];
  for (; p + 7 < pe; p += 8) {
    int2 e[8];
    int2 h[8];
#pragma unroll
    for (int u = 0; u < 8; ++u) e[u] = ld_nt8(csc + p + u);
#pragma unroll
    for (int u = 0; u < 8; ++u) h[u] = *(const int2*)(plane + (size_t)e[u].x * 64);
#pragma unroll
    for (int u = 0; u < 8; ++u) fma_fp8x8(acc, __int_as_float(e[u].y), h[u]);
  }
  for (; p + 1 < pe; p += 2) {
    int2 e0 = ld_nt8(csc + p), e1 = ld_nt8(csc + p + 1);
    int2 h0 = *(const int2*)(plane + (size_t)e0.x * 64);
    int2 h1 = *(const int2*)(plane + (size_t)e1.x * 64);
    fma_fp8x8(acc, __int_as_float(e0.y), h0);
    fma_fp8x8(acc, __int_as_float(e1.y), h1);
  }
  if (p < pe) {
    int2 e0 = ld_nt8(csc + p);
    int2 h0 = *(const int2*)(plane + (size_t)e0.x * 64);
    fma_fp8x8(acc, __int_as_float(e0.y), h0);
  }

  float dn = dinv[n];
#pragma unroll
  for (int q = 0; q < 8; ++q) acc[q] = dn * acc[q] + bias[f8 + q];
  if (do_bn) {
#pragma unroll
    for (int q = 0; q < 8; ++q) {
      float s = gamma[f8 + q] * rsqrtf(var[f8 + q] + 1e-5f);
      float v = (acc[q] - mean[f8 + q]) * s + beta[f8 + q];
      acc[q] = v > 0.f ? v : 0.f;
    }
  }
  union { short8 s; u64 u[2]; } cv;
#pragma unroll
  for (int q = 0; q < 8; ++q) cv.s[q] = (short)f2bf(acc[q]);
  u64* ap = (u64*)(A + (size_t)n * HD + f8);
  __builtin_nontemporal_store(cv.u[0], ap);
  __builtin_nontemporal_store(cv.u[1], ap + 1);
}

// ---- shared MFMA core (operands swapped: mfma(W_frag, A_frag)).
// Epilogue: bf16 B + fp8 shadow planes (B8a=feat0-63, B8b=feat64-127).
__device__ __forceinline__ void gemm_core(const u16* sw, const short8* afr,
                                          int m, int qd, int arow,
                                          const float* __restrict__ dinv,
                                          u16* __restrict__ B, u8* __restrict__ B8,
                                          int N) {
  const bool ok = (arow < N);
  const float dr = ok ? dinv[arow] : 0.f;
#pragma unroll
  for (int c = 0; c < 8; ++c) {
    f32x4 acc = {0.f, 0.f, 0.f, 0.f};
    const int n = c * 16 + m;
#pragma unroll
    for (int s = 0; s < 4; ++s) {
      short8 bfr = *(const short8*)(sw + n * 136 + 32 * s + 8 * qd);
      acc = __builtin_amdgcn_mfma_f32_16x16x32_bf16(bfr, afr[s], acc, 0, 0, 0);
    }
    if (ok) {
      float v0 = dr * acc[0], v1 = dr * acc[1], v2 = dr * acc[2], v3 = dr * acc[3];
      u16x4 o;
      o[0] = f2bf(v0); o[1] = f2bf(v1); o[2] = f2bf(v2); o[3] = f2bf(v3);
      const int fc = c * 16 + qd * 4;
      *(u16x4*)(B + (size_t)arow * HD + fc) = o;
      int w8 = 0;
      w8 = __builtin_amdgcn_cvt_pk_fp8_f32(v0, v1, w8, false);
      w8 = __builtin_amdgcn_cvt_pk_fp8_f32(v2, v3, w8, true);
      u8* pl = (fc < 64) ? (B8 + (size_t)arow * 64 + fc)
                         : (B8 + (size_t)N * 64 + (size_t)arow * 64 + (fc - 64));
      *(int*)pl = w8;
    }
  }
}

__device__ __forceinline__ void stage_w(const u16* __restrict__ Wt, u16* sw, int t) {
  const uint32_t* src = (const uint32_t*)Wt;
  uint32_t* dst = (uint32_t*)sw;
#pragma unroll
  for (int k = 0; k < 32; ++k) {
    int q = t + k * 256;
    int r = q >> 6;
    int u = q & 63;
    dst[r * 68 + u] = src[r * 64 + u];
  }
}

// layer-0 GEMM with fused h0 construction: reads x[N,64] fp32 directly.
__global__ __launch_bounds__(256)
void gemm0_k(const float* __restrict__ x, const u16* __restrict__ Wt,
             const float* __restrict__ dinv, u16* __restrict__ B,
             u8* __restrict__ B8, int N) {
  __shared__ u16 sw[128 * 136];
  const int t = threadIdx.x;
  stage_w(Wt, sw, t);
  __syncthreads();
  const int w = t >> 6;
  const int lane = t & 63;
  const int m = lane & 15;
  const int qd = lane >> 4;
  const int arow = blockIdx.x * 64 + w * 16 + m;
  short8 afr[4];
  if (arow < N) {
    const float* xp = x + (size_t)arow * 64;
    float v0[8], v1[8];
    *(float4*)&v0[0] = *(const float4*)(xp + 8 * qd);
    *(float4*)&v0[4] = *(const float4*)(xp + 8 * qd + 4);
    *(float4*)&v1[0] = *(const float4*)(xp + 32 + 8 * qd);
    *(float4*)&v1[4] = *(const float4*)(xp + 32 + 8 * qd + 4);
#pragma unroll
    for (int j = 0; j < 8; ++j) {
      bool n0 = isnan(v0[j]), n1 = isnan(v1[j]);
      afr[0][j] = (short)f2bf(n0 ? 0.f : v0[j]);
      afr[1][j] = (short)f2bf(n1 ? 0.f : v1[j]);
      afr[2][j] = (short)(n0 ? 0x3F80 : 0);
      afr[3][j] = (short)(n1 ? 0x3F80 : 0);
    }
  } else {
    short8 z = {0, 0, 0, 0, 0, 0, 0, 0};
#pragma unroll
    for (int s = 0; s < 4; ++s) afr[s] = z;
  }
  gemm_core(sw, afr, m, qd, arow, dinv, B, B8, N);
}

// generic GEMM: B = dinv-scaled rows of (A @ W), A bf16
__global__ __launch_bounds__(256)
void gemm_k(const u16* __restrict__ A, const u16* __restrict__ Wt,
            const float* __restrict__ dinv, u16* __restrict__ B,
            u8* __restrict__ B8, int N) {
  __shared__ u16 sw[128 * 136];
  const int t = threadIdx.x;
  stage_w(Wt, sw, t);
  __syncthreads();
  const int w = t >> 6;
  const int lane = t & 63;
  const int m = lane & 15;
  const int qd = lane >> 4;
  const int arow = blockIdx.x * 64 + w * 16 + m;
  short8 afr[4];
  if (arow < N) {
    const short8* ap = (const short8*)(A + (size_t)arow * HD);
#pragma unroll
    for (int s = 0; s < 4; ++s) afr[s] = ap[4 * s + qd];
  } else {
    short8 z = {0, 0, 0, 0, 0, 0, 0, 0};
#pragma unroll
    for (int s = 0; s < 4; ++s) afr[s] = z;
  }
  gemm_core(sw, afr, m, qd, arow, dinv, B, B8, N);
}

__device__ __forceinline__ int seg_lower_bound(const int* b32, int N, int b) {
  int lo = 0, hi = N;
  while (lo < hi) {
    int mid = (lo + hi) >> 1;
    if (b32[mid] < b) lo = mid + 1; else hi = mid;
  }
  return lo;
}

// two-stage mean pool, stage 1 (bf16 input); atomic-free partials.
__global__ __launch_bounds__(128)
void pool1_k(const u16* __restrict__ A, const int* __restrict__ b32,
             float* __restrict__ part, int N) {
  __shared__ int sb[2];
  int b = blockIdx.y;
  if (threadIdx.x < 2) sb[threadIdx.x] = seg_lower_bound(b32, N, b + threadIdx.x);
  __syncthreads();
  int s = sb[0], e = sb[1];
  int j = threadIdx.x;
  float a0 = 0.f, a1 = 0.f, a2 = 0.f, a3 = 0.f;
  int len = e - s;
  if (len > 0) {
    int nch = gridDim.x;
    int ch = (len + nch - 1) / nch;
    int lo = s + blockIdx.x * ch;
    int hi = lo + ch; if (hi > e) hi = e;
    int n = lo;
    for (; n + 3 < hi; n += 4) {
      a0 += bf2f(A[(size_t)(n + 0) * HD + j]);
      a1 += bf2f(A[(size_t)(n + 1) * HD + j]);
      a2 += bf2f(A[(size_t)(n + 2) * HD + j]);
      a3 += bf2f(A[(size_t)(n + 3) * HD + j]);
    }
    for (; n < hi; ++n) a0 += bf2f(A[(size_t)n * HD + j]);
  }
  part[((size_t)b * PCH + blockIdx.x) * HD + j] = (a0 + a1) + (a2 + a3);
}

// out = gelu((mean)@mW1+mb1) @ mW2 + mb2 ; mean from PCH partials
__global__ __launch_bounds__(128)
void mlp_k(const float* __restrict__ part, const int* __restrict__ b32,
           const float* __restrict__ mW1, const float* __restrict__ mb1,
           const float* __restrict__ mW2, const float* __restrict__ mb2,
           float* __restrict__ out, int N) {
  __shared__ float sg[128];
  __shared__ float st[128];
  __shared__ int sb[2];
  int b = blockIdx.x, j = threadIdx.x;
  if (j < 2) sb[j] = seg_lower_bound(b32, N, b + j);
  __syncthreads();
  int cnt = sb[1] - sb[0];
  float inv = 1.0f / (float)(cnt > 0 ? cnt : 1);
  float s0 = 0.f;
#pragma unroll
  for (int c = 0; c < PCH; ++c) s0 += part[((size_t)b * PCH + c) * HD + j];
  sg[j] = s0 * inv;
  __syncthreads();
  float s = mb1[j];
#pragma unroll 4
  for (int i = 0; i < 128; ++i) s += sg[i] * mW1[i * 128 + j];
  float ge = 0.5f * s * (1.0f + erff(s * 0.70710678118654752f));
  st[j] = ge;
  __syncthreads();
  if (j < OUTD) {
    float o = mb2[j];
#pragma unroll 4
    for (int k = 0; k < 128; ++k) o += st[k] * mW2[k * OUTD + j];
    out[b * OUTD + j] = o;
  }
}

// ---------------------------------------------------------------- launch
extern "C" void kernel_launch(void* const* d_in, const int* in_sizes, int n_in,
                              void* d_out, int out_size, void* d_ws, size_t ws_size,
                              hipStream_t stream) {
  const float* x   = (const float*)d_in[0];
  const int* ei    = (const int*)d_in[1];
  const float* ea  = (const float*)d_in[2];
  const int* bt    = (const int*)d_in[3];
  const float* W0  = (const float*)d_in[4];
  const float* b0  = (const float*)d_in[5];
  const float* W1  = (const float*)d_in[6];
  const float* b1  = (const float*)d_in[7];
  const float* W2  = (const float*)d_in[8];
  const float* b2  = (const float*)d_in[9];
  const float* bng = (const float*)d_in[10];
  const float* bnb = (const float*)d_in[11];
  const float* bnm = (const float*)d_in[12];
  const float* bnv = (const float*)d_in[13];
  const float* mW1 = (const float*)d_in[14];
  const float* mb1 = (const float*)d_in[15];
  const float* mW2 = (const float*)d_in[16];
  const float* mb2 = (const float*)d_in[17];
  float* out = (float*)d_out;

  const int N = in_sizes[0] / 64;      // 50000  (rows fit in 16 bits)
  const int E = in_sizes[2];           // 800000

  char* ws = (char*)d_ws;
  size_t NB2 = (size_t)N * HD * 2;     // bf16 feature buffer
  u16* A       = (u16*)(ws);
  u16* B       = (u16*)(ws + NB2);
  char* q      = ws + 2 * NB2;
  u8*  B8      = (u8*)q;               q += (size_t)N * HD;   // 2 fp8 planes
  float* part  = (float*)q;            q += (size_t)GD * PCH * HD * 4;
  u16* Wt      = (u16*)q;              q += (size_t)3 * HD * HD * 2;
  int2* csc    = (int2*)q;             q += (size_t)E * 8;
  int2* tmp    = (int2*)q;             q += (size_t)E * 8;
  int gE  = (E + 255) / 256;
  int*   Hist  = (int*)q;              q += (size_t)gE * 256 * 4;
  int*   Off   = (int*)q;              q += (size_t)gE * 256 * 4;
  int*   totals= (int*)q;              q += 256 * 4;
  float* dinv  = (float*)q;            q += (size_t)N * 4;
  int*   offs  = (int*)q;              q += (size_t)(N + 2) * 4;
  int*   b32   = (int*)q;              q += (size_t)N * 4;

  dim3 blk(256);
  int gN   = (N + 255) / 256;
  int nbuk = gN;                       // col buckets (col>>8)

  hist_k<<<gE, blk, 0, stream>>>(ei, bt, b32, Hist, W0, W1, W2, Wt, offs, E, N);
  scan_k<<<nbuk, blk, 0, stream>>>(Hist, Off, totals, gE);
  scat_k<<<gE, blk, 0, stream>>>(ei, ea, totals, Off, tmp, E, N, nbuk);
  sort_k<<<nbuk, blk, 0, stream>>>(tmp, totals, csc, offs, dinv, N, nbuk);

  int gGemm = (N + 63) / 64;
  int nbh  = (N + 31) / 32;
  int nb4  = (nbh + 3) / 4;
  int gAgg = nb4 * 8;

  // layer 0 GEMM: C0 = dinv*(h0@W0)   (h0 built in the A-fragment load)
  gemm0_k<<<gGemm, 256, 0, stream>>>(x, Wt, dinv, B, B8, N);
  aggregate_k<<<gAgg, blk, 0, stream>>>(offs, csc, B, B8, dinv, b0,
                                        bng, bnb, bnm, bnv, 1, A, N, nbh);
  // layer 1
  gemm_k<<<gGemm, 256, 0, stream>>>(A, Wt + HD * HD, dinv, B, B8, N);
  aggregate_k<<<gAgg, blk, 0, stream>>>(offs, csc, B, B8, dinv, b1,
                                        bng, bnb, bnm, bnv, 1, A, N, nbh);
  // layer 2 (no bn/relu)
  gemm_k<<<gGemm, 256, 0, stream>>>(A, Wt + 2 * HD * HD, dinv, B, B8, N);
  aggregate_k<<<gAgg, blk, 0, stream>>>(offs, csc, B, B8, dinv, b2,
                                        bng, bnb, bnm, bnv, 0, A, N, nbh);

  dim3 pgrid(PCH, GD);
  pool1_k<<<pgrid, 128, 0, stream>>>(A, b32, part, N);
  mlp_k<<<GD, 128, 0, stream>>>(part, b32, mW1, mb1, mW2, mb2, out, N);
}